// Round 7
// baseline (324.083 us; speedup 1.0000x reference)
//
#include <hip/hip_runtime.h>
#include <hip/hip_bf16.h>

#define PB 8
#define PS 1024
#define PD 512
#define PH 8

typedef __attribute__((ext_vector_type(8))) short short8;
typedef __attribute__((ext_vector_type(4))) float f32x4;

__device__ inline ushort f2bf(float x) {
    union { float f; unsigned u; } c; c.f = x;
    unsigned u = c.u + 0x7fffu + ((c.u >> 16) & 1u);
    return (ushort)(u >> 16);
}
__device__ inline float bf2f(ushort u) {
    union { unsigned u; float f; } c; c.u = (unsigned)u << 16; return c.f;
}

__device__ inline void gload16(const void* g, void* l) {
    __builtin_amdgcn_global_load_lds(
        (const __attribute__((address_space(1))) void*)g,
        (__attribute__((address_space(3))) void*)l, 16, 0, 0);
}

// pack 8 consecutive f32 -> 8 bf16 (one uint4)
__device__ inline uint4 pack8(const float* src) {
    const float4 x = *(const float4*)src;
    const float4 y = *(const float4*)(src + 4);
    union { ushort u[8]; uint4 v; } pk;
    pk.u[0] = f2bf(x.x); pk.u[1] = f2bf(x.y); pk.u[2] = f2bf(x.z); pk.u[3] = f2bf(x.w);
    pk.u[4] = f2bf(y.x); pk.u[5] = f2bf(y.y); pk.u[6] = f2bf(y.z); pk.u[7] = f2bf(y.w);
    return pk.v;
}

// ---------------------------------------------------------------------------
// All three projections, reading f32 inputs directly (reg-staged f32->bf16).
// Grid (64, 2, 3): 128x256 tile, 4 waves 2x2 (wave tile 64x128), BK=64.
// z = 0:q -> qh, 1:k -> kh (head-split [(b*8+h)*1024+s][64]),
// z = 2:v -> vhT (plain transpose [(b*8+h)*64+d][1024 s]).
// ---------------------------------------------------------------------------
__global__ __launch_bounds__(256)
void proj3(const float* __restrict__ q, const float* __restrict__ k,
           const float* __restrict__ v, const float* __restrict__ Wq,
           const float* __restrict__ Wv, const float* __restrict__ bq,
           const float* __restrict__ bv, ushort* __restrict__ qh,
           ushort* __restrict__ kh, ushort* __restrict__ vhT)
{
    const int z = blockIdx.z;
    const float* A = (z == 0) ? q : (z == 1) ? k : v;
    const float* B = (z == 2) ? Wv : Wq;
    const float* bias = (z == 2) ? bv : bq;

    __shared__ __align__(16) ushort As[128 * 64];   // 16 KB
    __shared__ __align__(16) ushort Bs[256 * 64];   // 32 KB
    const int tid = threadIdx.x, lane = tid & 63, wave = tid >> 6;
    const int wr = wave >> 1, wc = wave & 1;
    const int bm = blockIdx.x * 128, bn = blockIdx.y * 256;

    f32x4 acc[4][8] = {};

    for (int k0 = 0; k0 < 512; k0 += 64) {
        // stage A: 1024 16B-chunks, lane-stride-16B (conflict-free ds_write)
#pragma unroll
        for (int jj = 0; jj < 4; ++jj) {
            const int c = tid + 256 * jj;
            const int row = c >> 3, col = (c & 7) * 8;
            *(uint4*)&As[c * 8] = pack8(A + (size_t)(bm + row) * 512 + k0 + col);
        }
        // stage B: 2048 chunks
#pragma unroll
        for (int jj = 0; jj < 8; ++jj) {
            const int c = tid + 256 * jj;
            const int row = c >> 3, col = (c & 7) * 8;
            *(uint4*)&Bs[c * 8] = pack8(B + (size_t)(bn + row) * 512 + k0 + col);
        }
        __syncthreads();
#pragma unroll
        for (int kk = 0; kk < 2; ++kk) {
            short8 af[4];
#pragma unroll
            for (int m = 0; m < 4; ++m)
                af[m] = *(const short8*)&As[(wr * 64 + m * 16 + (lane & 15)) * 64 + kk * 32 + (lane >> 4) * 8];
#pragma unroll
            for (int n = 0; n < 8; ++n) {
                const short8 bf = *(const short8*)&Bs[(wc * 128 + n * 16 + (lane & 15)) * 64 + kk * 32 + (lane >> 4) * 8];
#pragma unroll
                for (int m = 0; m < 4; ++m)
                    acc[m][n] = __builtin_amdgcn_mfma_f32_16x16x32_bf16(af[m], bf, acc[m][n], 0, 0, 0);
            }
        }
        __syncthreads();
    }

#pragma unroll
    for (int m = 0; m < 4; ++m)
#pragma unroll
        for (int n = 0; n < 8; ++n) {
            const int row0 = bm + wr * 64 + m * 16 + (lane >> 4) * 4;
            const int col  = bn + wc * 128 + n * 16 + (lane & 15);
            const int b = row0 >> 10, s0 = row0 & 1023;
            const int h = col >> 6, d = col & 63;
            const float bi = bias[col];
            if (z == 2) {
                ushort4 o;
                o.x = f2bf(acc[m][n][0] + bi);
                o.y = f2bf(acc[m][n][1] + bi);
                o.z = f2bf(acc[m][n][2] + bi);
                o.w = f2bf(acc[m][n][3] + bi);
                *(ushort4*)&vhT[((size_t)((b * 8 + h) * 64 + d)) * 1024 + s0] = o;
            } else {
                ushort* out = z ? kh : qh;
#pragma unroll
                for (int r = 0; r < 4; ++r)
                    out[(((size_t)(b * 8 + h)) * 1024 + s0 + r) * 64 + d] =
                        f2bf(acc[m][n][r] + bi);
            }
        }
}

// ---------------------------------------------------------------------------
// QK^T per (b,h): raw bf16 logits (x0.125) into the first 2KB of each score
// row's 4KB slot. Upper-triangular 128-blocks write f32 zeros (final value).
// ---------------------------------------------------------------------------
__global__ __launch_bounds__(256)
void qk_mfma(const ushort* __restrict__ qh, const ushort* __restrict__ kh,
             float* __restrict__ scores)
{
    const int kb = blockIdx.x, qb = blockIdx.y, bh = blockIdx.z;
    const int tid = threadIdx.x;
    if (kb > qb) {
        // masked region: write final zeros
        float* S = scores + ((size_t)bh << 20);
        const f32x4 z = {};
#pragma unroll
        for (int it = 0; it < 16; ++it) {
            const int f = it * 256 + tid;           // 4096 float4 total
            const int row = f >> 5, c4 = f & 31;
            __builtin_nontemporal_store(z,
                (f32x4*)&S[(size_t)(qb * 128 + row) * 1024 + kb * 128 + c4 * 4]);
        }
        return;
    }
    __shared__ __align__(16) ushort As[128 * 64];
    __shared__ __align__(16) ushort Bs[128 * 64];
    const int lane = tid & 63, wave = tid >> 6;
    const int wr = wave >> 1, wc = wave & 1;
    const ushort* Ab = qh + ((size_t)bh * PS + qb * 128) * 64;
    const ushort* Bb = kh + ((size_t)bh * PS + kb * 128) * 64;

#pragma unroll
    for (int i = 0; i < 4; ++i) {
        const int c = wave * 4 + i;
        gload16(Ab + c * 512 + lane * 8, &As[c * 512]);
        gload16(Bb + c * 512 + lane * 8, &Bs[c * 512]);
    }
    __syncthreads();

    f32x4 acc[4][4] = {};
    short8 af[2][4], bf[2][4];
#pragma unroll
    for (int kk = 0; kk < 2; ++kk) {
#pragma unroll
        for (int m = 0; m < 4; ++m)
            af[kk][m] = *(const short8*)&As[(wr * 64 + m * 16 + (lane & 15)) * 64 + kk * 32 + (lane >> 4) * 8];
#pragma unroll
        for (int n = 0; n < 4; ++n)
            bf[kk][n] = *(const short8*)&Bs[(wc * 64 + n * 16 + (lane & 15)) * 64 + kk * 32 + (lane >> 4) * 8];
    }
#pragma unroll
    for (int kk = 0; kk < 2; ++kk)
#pragma unroll
        for (int m = 0; m < 4; ++m)
#pragma unroll
            for (int n = 0; n < 4; ++n)
                acc[m][n] = __builtin_amdgcn_mfma_f32_16x16x32_bf16(af[kk][m], bf[kk][n], acc[m][n], 0, 0, 0);

    ushort* Sr = (ushort*)(scores + ((size_t)bh << 20));
#pragma unroll
    for (int m = 0; m < 4; ++m)
#pragma unroll
        for (int n = 0; n < 4; ++n)
#pragma unroll
            for (int r = 0; r < 4; ++r) {
                const int row = qb * 128 + wr * 64 + m * 16 + (lane >> 4) * 4 + r;
                const int col = kb * 128 + wc * 64 + n * 16 + (lane & 15);
                Sr[(size_t)row * 2048 + col] = f2bf(acc[m][n][r] * 0.125f);
            }
}

// ---------------------------------------------------------------------------
// Row softmax pipeline: pure streaming, NO LDS, NO barriers. Wave per row.
// Reads raw bf16 prefix, writes final f32 scores for cols < ceil128(i+1).
// ---------------------------------------------------------------------------
__global__ __launch_bounds__(1024)
void row_soft(float* __restrict__ scores, const float* __restrict__ gammas)
{
    const int bh = blockIdx.y, h = bh & 7;
    const int i = blockIdx.x * 16 + (threadIdx.x >> 6);
    const int lane = threadIdx.x & 63;
    const int lim = ((i >> 7) + 1) * 128;            // 128-block diagonal limit
    float* srow = scores + ((size_t)bh << 20) + ((size_t)i << 10);
    const ushort* rraw = (const ushort*)srow;
    const int base = lane * 16;

    union U8 { uint4 v; ushort u[8]; };
    float l[16];
    if (base <= i) {
        U8 a, c2;
        a.v  = *(const uint4*)(rraw + base);
        c2.v = *(const uint4*)(rraw + base + 8);
#pragma unroll
        for (int c = 0; c < 8; ++c) { l[c] = bf2f(a.u[c]); l[c + 8] = bf2f(c2.u[c]); }
#pragma unroll
        for (int c = 0; c < 16; ++c) if (base + c > i) l[c] = -3.0e38f;
    } else {
#pragma unroll
        for (int c = 0; c < 16; ++c) l[c] = -3.0e38f;
    }

    // softmax-1 max
    float m1 = -3.0e38f;
#pragma unroll
    for (int c = 0; c < 16; ++c) m1 = fmaxf(m1, l[c]);
#pragma unroll
    for (int off = 32; off; off >>= 1) m1 = fmaxf(m1, __shfl_xor(m1, off));

    // exp + in-lane inclusive cumsum
    float cum[16];
    float lsum = 0.f;
#pragma unroll
    for (int c = 0; c < 16; ++c) {
        const float e = (base + c <= i) ? __expf(l[c] - m1) : 0.f;
        lsum += e;
        cum[c] = lsum;
    }
    // single 64-lane scan of lane totals
    float incl = lsum;
#pragma unroll
    for (int off = 1; off < 64; off <<= 1) {
        const float y = __shfl_up(incl, off);
        if (lane >= off) incl += y;
    }
    const float excl = incl - lsum;
    const float es = __shfl(incl, 63);
    const float inv_es = 1.0f / es;
    const float gamma = -fabsf(gammas[h]);

    // decay + softmax-2 max
    float m2 = -3.0e38f;
#pragma unroll
    for (int c = 0; c < 16; ++c) {
        if (base + c <= i) {
            const float pe = (float)(i - (base + c));
            const float sfx = fmaxf((es - (excl + cum[c])) * inv_es, 0.f);
            const float dist = sqrtf(sfx * pe);
            const float eff = fmaxf(__expf(gamma * dist), 1e-5f);
            l[c] *= eff;
            m2 = fmaxf(m2, l[c]);
        }
    }
#pragma unroll
    for (int off = 32; off; off >>= 1) m2 = fmaxf(m2, __shfl_xor(m2, off));

    float s2 = 0.f;
#pragma unroll
    for (int c = 0; c < 16; ++c) {
        const float p = (base + c <= i) ? __expf(l[c] - m2) : 0.f;
        l[c] = p; s2 += p;
    }
#pragma unroll
    for (int off = 32; off; off >>= 1) s2 += __shfl_xor(s2, off);
    const float inv2 = 1.0f / s2;
#pragma unroll
    for (int c = 0; c < 16; ++c) l[c] *= inv2;

    // final scores (f32) for cols < lim; cols >= lim already zeroed by qk
    if (base < lim) {
#pragma unroll
        for (int g = 0; g < 4; ++g) {
            f32x4 v;
            v[0] = l[g * 4 + 0]; v[1] = l[g * 4 + 1];
            v[2] = l[g * 4 + 2]; v[3] = l[g * 4 + 3];
            __builtin_nontemporal_store(v, (f32x4*)&srow[base + g * 4]);
        }
    }
}

// ---------------------------------------------------------------------------
// PV: O[q,d] = sum_k P[q,k]*V^T[d,k]. NO LDS, NO barriers. A read directly
// from f32 scores (converted in-reg), B from plain V^T bf16. 4 waves 2x2,
// wave tile 64 q x 32 d, causal k-range.
// ---------------------------------------------------------------------------
__global__ __launch_bounds__(256)
void pv_mfma(const float* __restrict__ scores, const ushort* __restrict__ vhT,
             ushort* __restrict__ attn)
{
    const int qb = blockIdx.x, bh = blockIdx.y;
    const int b = bh >> 3, h = bh & 7;
    const int lane = threadIdx.x & 63, wave = threadIdx.x >> 6;
    const int wr = wave >> 1, wc = wave & 1;
    const int lg = lane >> 4, l15 = lane & 15;
    const float* S = scores + ((size_t)bh << 20);
    const ushort* VT = vhT + ((size_t)bh << 16);
    const int nt = 2 * (qb + 1);

    const float* pa[4];
#pragma unroll
    for (int m = 0; m < 4; ++m)
        pa[m] = S + (size_t)(qb * 128 + wr * 64 + m * 16 + l15) * 1024;
    const ushort* pb[2];
#pragma unroll
    for (int n = 0; n < 2; ++n)
        pb[n] = VT + (size_t)(wc * 32 + n * 16 + l15) * 1024;

    f32x4 acc[4][2] = {};
    union U8 { short8 s; ushort u[8]; };

    for (int t = 0; t < nt; ++t) {
        const int off = t * 64 + lg * 8;
        short8 af[2][4], bf[2][2];
#pragma unroll
        for (int kk = 0; kk < 2; ++kk)
#pragma unroll
            for (int m = 0; m < 4; ++m) {
                const float4 x = *(const float4*)&pa[m][off + kk * 32];
                const float4 y = *(const float4*)&pa[m][off + kk * 32 + 4];
                U8 pk;
                pk.u[0] = f2bf(x.x); pk.u[1] = f2bf(x.y);
                pk.u[2] = f2bf(x.z); pk.u[3] = f2bf(x.w);
                pk.u[4] = f2bf(y.x); pk.u[5] = f2bf(y.y);
                pk.u[6] = f2bf(y.z); pk.u[7] = f2bf(y.w);
                af[kk][m] = pk.s;
            }
#pragma unroll
        for (int kk = 0; kk < 2; ++kk)
#pragma unroll
            for (int n = 0; n < 2; ++n)
                bf[kk][n] = *(const short8*)&pb[n][off + kk * 32];
#pragma unroll
        for (int kk = 0; kk < 2; ++kk)
#pragma unroll
            for (int m = 0; m < 4; ++m)
#pragma unroll
                for (int n = 0; n < 2; ++n)
                    acc[m][n] = __builtin_amdgcn_mfma_f32_16x16x32_bf16(af[kk][m], bf[kk][n], acc[m][n], 0, 0, 0);
    }

#pragma unroll
    for (int m = 0; m < 4; ++m)
#pragma unroll
        for (int n = 0; n < 2; ++n)
#pragma unroll
            for (int r = 0; r < 4; ++r) {
                const int row = qb * 128 + wr * 64 + m * 16 + lg * 4 + r;
                const int d = wc * 32 + n * 16 + l15;
                attn[((size_t)(b * 1024 + row)) * 512 + h * 64 + d] = f2bf(acc[m][n][r]);
            }
}

// ---------------------------------------------------------------------------
// Output GEMM: f32 out = attn(bf16) @ Wo^T(f32, reg-staged) + bo
// ---------------------------------------------------------------------------
__global__ __launch_bounds__(256)
void gemm_out(const ushort* __restrict__ A, const float* __restrict__ B,
              const float* __restrict__ bias, float* __restrict__ out)
{
    __shared__ __align__(16) ushort As[128 * 64];
    __shared__ __align__(16) ushort Bs[128 * 64];
    const int tid = threadIdx.x;
    const int lane = tid & 63;
    const int wave = tid >> 6;
    const int wr = wave >> 1, wc = wave & 1;
    const int bm = blockIdx.x * 128, bn = blockIdx.y * 128;
    const int lrow = lane >> 3;
    const int lcol = (lane & 7) * 8;

    f32x4 acc[4][4] = {};

    for (int k0 = 0; k0 < 512; k0 += 64) {
#pragma unroll
        for (int i = 0; i < 4; ++i) {
            const int c = wave * 4 + i;
            gload16(A + (size_t)(bm + c * 8 + lrow) * 512 + k0 + lcol, &As[c * 512]);
        }
        // stage B from f32: 1024 16B-chunks, lane-stride-16B
#pragma unroll
        for (int jj = 0; jj < 4; ++jj) {
            const int c = tid + 256 * jj;
            const int row = c >> 3, col = (c & 7) * 8;
            *(uint4*)&Bs[c * 8] = pack8(B + (size_t)(bn + row) * 512 + k0 + col);
        }
        __syncthreads();
        short8 af[2][4], bf[2][4];
#pragma unroll
        for (int kk = 0; kk < 2; ++kk) {
#pragma unroll
            for (int m = 0; m < 4; ++m)
                af[kk][m] = *(const short8*)&As[(wr * 64 + m * 16 + (lane & 15)) * 64 + kk * 32 + (lane >> 4) * 8];
#pragma unroll
            for (int n = 0; n < 4; ++n)
                bf[kk][n] = *(const short8*)&Bs[(wc * 64 + n * 16 + (lane & 15)) * 64 + kk * 32 + (lane >> 4) * 8];
        }
#pragma unroll
        for (int kk = 0; kk < 2; ++kk)
#pragma unroll
            for (int m = 0; m < 4; ++m)
#pragma unroll
                for (int n = 0; n < 4; ++n)
                    acc[m][n] = __builtin_amdgcn_mfma_f32_16x16x32_bf16(af[kk][m], bf[kk][n], acc[m][n], 0, 0, 0);
        __syncthreads();
    }

#pragma unroll
    for (int m = 0; m < 4; ++m)
#pragma unroll
        for (int n = 0; n < 4; ++n)
#pragma unroll
            for (int r = 0; r < 4; ++r) {
                const int row = bm + wr * 64 + m * 16 + (lane >> 4) * 4 + r;
                const int col = bn + wc * 64 + n * 16 + (lane & 15);
                out[(size_t)row * 512 + col] = acc[m][n][r] + bias[col];
            }
}

// ---------------------------------------------------------------------------
extern "C" void kernel_launch(void* const* d_in, const int* in_sizes, int n_in,
                              void* d_out, int out_size, void* d_ws, size_t ws_size,
                              hipStream_t stream)
{
    const float* q      = (const float*)d_in[0];
    const float* k      = (const float*)d_in[1];
    const float* v      = (const float*)d_in[2];
    const float* Wq     = (const float*)d_in[4];
    const float* bq     = (const float*)d_in[5];
    const float* Wv     = (const float*)d_in[6];
    const float* bv     = (const float*)d_in[7];
    const float* Wo     = (const float*)d_in[8];
    const float* bo     = (const float*)d_in[9];
    const float* gammas = (const float*)d_in[10];

    float* out    = (float*)d_out;                       // [8,1024,512] f32
    float* scores = out + (size_t)PB * PS * PD;          // [64,1024,1024] f32

    char* w = (char*)d_ws;
    ushort* qh   = (ushort*)(w);                         // 8 MB
    ushort* kh   = (ushort*)(w + (8u  << 20));           // 8 MB
    ushort* vhT  = (ushort*)(w + (16u << 20));           // 8 MB (plain transpose)
    ushort* attn = (ushort*)(w + (24u << 20));           // 8 MB

    proj3<<<dim3(64, 2, 3), 256, 0, stream>>>(q, k, v, Wq, Wv, bq, bv, qh, kh, vhT);

    qk_mfma<<<dim3(8, 8, 64), 256, 0, stream>>>(qh, kh, scores);
    row_soft<<<dim3(64, 64), 1024, 0, stream>>>(scores, gammas);
    pv_mfma<<<dim3(8, 64), 256, 0, stream>>>(scores, vhT, attn);

    gemm_out<<<dim3(64, 4), 256, 0, stream>>>(attn, Wo, bo, out);
}

// Round 8
// 250.310 us; speedup vs baseline: 1.2947x; 1.2947x over previous
//
#include <hip/hip_runtime.h>
#include <hip/hip_bf16.h>

#define PB 8
#define PS 1024
#define PD 512
#define PH 8

typedef __attribute__((ext_vector_type(8))) short short8;
typedef __attribute__((ext_vector_type(4))) float f32x4;

__device__ inline ushort f2bf(float x) {
    union { float f; unsigned u; } c; c.f = x;
    unsigned u = c.u + 0x7fffu + ((c.u >> 16) & 1u);
    return (ushort)(u >> 16);
}
__device__ inline float bf2f(ushort u) {
    union { unsigned u; float f; } c; c.u = (unsigned)u << 16; return c.f;
}

__device__ inline void gload16(const void* g, void* l) {
    __builtin_amdgcn_global_load_lds(
        (const __attribute__((address_space(1))) void*)g,
        (__attribute__((address_space(3))) void*)l, 16, 0, 0);
}

// ---------------------------------------------------------------------------
// One dispatch for all 6 bf16 casts.
// ---------------------------------------------------------------------------
__global__ __launch_bounds__(256)
void cast_all(const float* __restrict__ q, const float* __restrict__ k,
              const float* __restrict__ v, const float* __restrict__ Wq,
              const float* __restrict__ Wv, const float* __restrict__ Wo,
              ushort* __restrict__ q_bf, ushort* __restrict__ k_bf,
              ushort* __restrict__ v_bf, ushort* __restrict__ Wq_bf,
              ushort* __restrict__ Wv_bf, ushort* __restrict__ Wo_bf)
{
    const int bid = blockIdx.x;
    const float* s; ushort* d; int base;
    if      (bid < 4096)  { s = q;  d = q_bf;  base = bid; }
    else if (bid < 8192)  { s = k;  d = k_bf;  base = bid - 4096; }
    else if (bid < 12288) { s = v;  d = v_bf;  base = bid - 8192; }
    else if (bid < 12544) { s = Wq; d = Wq_bf; base = bid - 12288; }
    else if (bid < 12800) { s = Wv; d = Wv_bf; base = bid - 12544; }
    else                  { s = Wo; d = Wo_bf; base = bid - 12800; }
    const int i = base * 256 + threadIdx.x;
    const float4 x = ((const float4*)s)[i];
    ushort4 o;
    o.x = f2bf(x.x); o.y = f2bf(x.y); o.z = f2bf(x.z); o.w = f2bf(x.w);
    ((ushort4*)d)[i] = o;
}

// ---------------------------------------------------------------------------
// All three projections in one dispatch (blockIdx.z = 0:q, 1:k, 2:v).
// z<2 -> bf16 head-split [(b*8+h)*1024+s][64]; z==2 -> plain V^T
// vhT[(b*8+h)*64+d][1024 s].
// ---------------------------------------------------------------------------
__global__ __launch_bounds__(256)
void proj3(const ushort* __restrict__ q_bf, const ushort* __restrict__ k_bf,
           const ushort* __restrict__ v_bf, const ushort* __restrict__ Wq_bf,
           const ushort* __restrict__ Wv_bf, const float* __restrict__ bq,
           const float* __restrict__ bv, ushort* __restrict__ qh,
           ushort* __restrict__ kh, ushort* __restrict__ vhT)
{
    const int z = blockIdx.z;
    const ushort* A = (z == 0) ? q_bf : (z == 1) ? k_bf : v_bf;
    const ushort* B = (z == 2) ? Wv_bf : Wq_bf;
    const float* bias = (z == 2) ? bv : bq;

    __shared__ __align__(16) ushort As[128 * 64];
    __shared__ __align__(16) ushort Bs[128 * 64];
    const int tid = threadIdx.x;
    const int lane = tid & 63;
    const int wave = tid >> 6;
    const int wr = wave >> 1, wc = wave & 1;
    const int bm = blockIdx.x * 128, bn = blockIdx.y * 128;
    const int lrow = lane >> 3;
    const int lcol = (lane & 7) * 8;

    f32x4 acc[4][4] = {};

    for (int k0 = 0; k0 < 512; k0 += 64) {
#pragma unroll
        for (int i = 0; i < 4; ++i) {
            const int c = wave * 4 + i;
            gload16(A + (size_t)(bm + c * 8 + lrow) * 512 + k0 + lcol, &As[c * 512]);
            gload16(B + (size_t)(bn + c * 8 + lrow) * 512 + k0 + lcol, &Bs[c * 512]);
        }
        __syncthreads();
        short8 af[2][4], bf[2][4];
#pragma unroll
        for (int kk = 0; kk < 2; ++kk) {
#pragma unroll
            for (int m = 0; m < 4; ++m)
                af[kk][m] = *(const short8*)&As[(wr * 64 + m * 16 + (lane & 15)) * 64 + kk * 32 + (lane >> 4) * 8];
#pragma unroll
            for (int n = 0; n < 4; ++n)
                bf[kk][n] = *(const short8*)&Bs[(wc * 64 + n * 16 + (lane & 15)) * 64 + kk * 32 + (lane >> 4) * 8];
        }
#pragma unroll
        for (int kk = 0; kk < 2; ++kk)
#pragma unroll
            for (int m = 0; m < 4; ++m)
#pragma unroll
                for (int n = 0; n < 4; ++n)
                    acc[m][n] = __builtin_amdgcn_mfma_f32_16x16x32_bf16(af[kk][m], bf[kk][n], acc[m][n], 0, 0, 0);
        __syncthreads();
    }

#pragma unroll
    for (int m = 0; m < 4; ++m)
#pragma unroll
        for (int n = 0; n < 4; ++n) {
            const int row0 = bm + wr * 64 + m * 16 + (lane >> 4) * 4;
            const int col  = bn + wc * 64 + n * 16 + (lane & 15);
            const int b = row0 >> 10, s0 = row0 & 1023;
            const int h = col >> 6, d = col & 63;
            if (z == 2) {
                ushort4 o;
                o.x = f2bf(acc[m][n][0] + bias[col]);
                o.y = f2bf(acc[m][n][1] + bias[col]);
                o.z = f2bf(acc[m][n][2] + bias[col]);
                o.w = f2bf(acc[m][n][3] + bias[col]);
                *(ushort4*)&vhT[((size_t)((b * 8 + h) * 64 + d)) * 1024 + s0] = o;
            } else {
                ushort* out = z ? kh : qh;
#pragma unroll
                for (int r = 0; r < 4; ++r)
                    out[(((size_t)(b * 8 + h)) * 1024 + s0 + r) * 64 + d] =
                        f2bf(acc[m][n][r] + bias[col]);
            }
        }
}

// ---------------------------------------------------------------------------
// QK^T per (b,h): raw bf16 logits (x0.125) into the first 2KB of each score
// row's 4KB slot. Upper-triangular 128-blocks write f32 zeros (final value).
// Flat grid, bh fastest-varying -> same-bh blocks share an XCD's L2.
// ---------------------------------------------------------------------------
__global__ __launch_bounds__(256)
void qk_mfma(const ushort* __restrict__ qh, const ushort* __restrict__ kh,
             float* __restrict__ scores)
{
    const int d0 = blockIdx.x;           // 0..4095
    const int bh = d0 & 63;
    const int pair = d0 >> 6;            // 0..63
    const int kb = pair & 7, qb = pair >> 3;
    const int tid = threadIdx.x;
    if (kb > qb) {
        // masked region: write final zeros
        float* S = scores + ((size_t)bh << 20);
        const f32x4 z = {};
#pragma unroll
        for (int it = 0; it < 16; ++it) {
            const int f = it * 256 + tid;           // 4096 float4 total
            const int row = f >> 5, c4 = f & 31;
            __builtin_nontemporal_store(z,
                (f32x4*)&S[(size_t)(qb * 128 + row) * 1024 + kb * 128 + c4 * 4]);
        }
        return;
    }
    __shared__ __align__(16) ushort As[128 * 64];
    __shared__ __align__(16) ushort Bs[128 * 64];
    const int lane = tid & 63, wave = tid >> 6;
    const int wr = wave >> 1, wc = wave & 1;
    const ushort* Ab = qh + ((size_t)bh * PS + qb * 128) * 64;
    const ushort* Bb = kh + ((size_t)bh * PS + kb * 128) * 64;

#pragma unroll
    for (int i = 0; i < 4; ++i) {
        const int c = wave * 4 + i;
        gload16(Ab + c * 512 + lane * 8, &As[c * 512]);
        gload16(Bb + c * 512 + lane * 8, &Bs[c * 512]);
    }
    __syncthreads();

    f32x4 acc[4][4] = {};
    short8 af[2][4], bf[2][4];
#pragma unroll
    for (int kk = 0; kk < 2; ++kk) {
#pragma unroll
        for (int m = 0; m < 4; ++m)
            af[kk][m] = *(const short8*)&As[(wr * 64 + m * 16 + (lane & 15)) * 64 + kk * 32 + (lane >> 4) * 8];
#pragma unroll
        for (int n = 0; n < 4; ++n)
            bf[kk][n] = *(const short8*)&Bs[(wc * 64 + n * 16 + (lane & 15)) * 64 + kk * 32 + (lane >> 4) * 8];
    }
#pragma unroll
    for (int kk = 0; kk < 2; ++kk)
#pragma unroll
        for (int m = 0; m < 4; ++m)
#pragma unroll
            for (int n = 0; n < 4; ++n)
                acc[m][n] = __builtin_amdgcn_mfma_f32_16x16x32_bf16(af[kk][m], bf[kk][n], acc[m][n], 0, 0, 0);

    ushort* Sr = (ushort*)(scores + ((size_t)bh << 20));
#pragma unroll
    for (int m = 0; m < 4; ++m)
#pragma unroll
        for (int n = 0; n < 4; ++n)
#pragma unroll
            for (int r = 0; r < 4; ++r) {
                const int row = qb * 128 + wr * 64 + m * 16 + (lane >> 4) * 4 + r;
                const int col = kb * 128 + wc * 64 + n * 16 + (lane & 15);
                Sr[(size_t)row * 2048 + col] = f2bf(acc[m][n][r] * 0.125f);
            }
}

// ---------------------------------------------------------------------------
// Row softmax pipeline: pure streaming, NO LDS, NO barriers. Wave per row.
// Reads raw bf16 prefix, writes final f32 scores for cols < ceil128(i+1).
// Flat grid, bh fastest-varying.
// ---------------------------------------------------------------------------
__global__ __launch_bounds__(1024)
void row_soft(float* __restrict__ scores, const float* __restrict__ gammas)
{
    const int d0 = blockIdx.x;           // 0..4095
    const int bh = d0 & 63, h = bh & 7;
    const int i = (d0 >> 6) * 16 + (threadIdx.x >> 6);
    const int lane = threadIdx.x & 63;
    const int lim = ((i >> 7) + 1) * 128;            // 128-block diagonal limit
    float* srow = scores + ((size_t)bh << 20) + ((size_t)i << 10);
    const ushort* rraw = (const ushort*)srow;
    const int base = lane * 16;

    union U8 { uint4 v; ushort u[8]; };
    float l[16];
    if (base <= i) {
        U8 a, c2;
        a.v  = *(const uint4*)(rraw + base);
        c2.v = *(const uint4*)(rraw + base + 8);
#pragma unroll
        for (int c = 0; c < 8; ++c) { l[c] = bf2f(a.u[c]); l[c + 8] = bf2f(c2.u[c]); }
#pragma unroll
        for (int c = 0; c < 16; ++c) if (base + c > i) l[c] = -3.0e38f;
    } else {
#pragma unroll
        for (int c = 0; c < 16; ++c) l[c] = -3.0e38f;
    }

    // softmax-1 max
    float m1 = -3.0e38f;
#pragma unroll
    for (int c = 0; c < 16; ++c) m1 = fmaxf(m1, l[c]);
#pragma unroll
    for (int off = 32; off; off >>= 1) m1 = fmaxf(m1, __shfl_xor(m1, off));

    // exp + in-lane inclusive cumsum
    float cum[16];
    float lsum = 0.f;
#pragma unroll
    for (int c = 0; c < 16; ++c) {
        const float e = (base + c <= i) ? __expf(l[c] - m1) : 0.f;
        lsum += e;
        cum[c] = lsum;
    }
    // single 64-lane scan of lane totals
    float incl = lsum;
#pragma unroll
    for (int off = 1; off < 64; off <<= 1) {
        const float y = __shfl_up(incl, off);
        if (lane >= off) incl += y;
    }
    const float excl = incl - lsum;
    const float es = __shfl(incl, 63);
    const float inv_es = 1.0f / es;
    const float gamma = -fabsf(gammas[h]);

    // decay + softmax-2 max
    float m2 = -3.0e38f;
#pragma unroll
    for (int c = 0; c < 16; ++c) {
        if (base + c <= i) {
            const float pe = (float)(i - (base + c));
            const float sfx = fmaxf((es - (excl + cum[c])) * inv_es, 0.f);
            const float dist = sqrtf(sfx * pe);
            const float eff = fmaxf(__expf(gamma * dist), 1e-5f);
            l[c] *= eff;
            m2 = fmaxf(m2, l[c]);
        }
    }
#pragma unroll
    for (int off = 32; off; off >>= 1) m2 = fmaxf(m2, __shfl_xor(m2, off));

    float s2 = 0.f;
#pragma unroll
    for (int c = 0; c < 16; ++c) {
        const float p = (base + c <= i) ? __expf(l[c] - m2) : 0.f;
        l[c] = p; s2 += p;
    }
#pragma unroll
    for (int off = 32; off; off >>= 1) s2 += __shfl_xor(s2, off);
    const float inv2 = 1.0f / s2;
#pragma unroll
    for (int c = 0; c < 16; ++c) l[c] *= inv2;

    // final scores (f32) for cols < lim; cols >= lim already zeroed by qk
    if (base < lim) {
#pragma unroll
        for (int g = 0; g < 4; ++g) {
            f32x4 v;
            v[0] = l[g * 4 + 0]; v[1] = l[g * 4 + 1];
            v[2] = l[g * 4 + 2]; v[3] = l[g * 4 + 3];
            __builtin_nontemporal_store(v, (f32x4*)&srow[base + g * 4]);
        }
    }
}

// ---------------------------------------------------------------------------
// PV: O[q,d] = sum_k P[q,k]*V^T[d,k]. NO LDS, NO barriers. A read directly
// from f32 scores (converted in-reg), B from plain V^T bf16. 4 waves 2x2,
// wave tile 64 q x 32 d, causal k-range. Flat grid, bh fastest-varying.
// ---------------------------------------------------------------------------
__global__ __launch_bounds__(256)
void pv_mfma(const float* __restrict__ scores, const ushort* __restrict__ vhT,
             ushort* __restrict__ attn)
{
    const int d0 = blockIdx.x;           // 0..511
    const int bh = d0 & 63, qb = d0 >> 6;
    const int b = bh >> 3, h = bh & 7;
    const int lane = threadIdx.x & 63, wave = threadIdx.x >> 6;
    const int wr = wave >> 1, wc = wave & 1;
    const int lg = lane >> 4, l15 = lane & 15;
    const float* S = scores + ((size_t)bh << 20);
    const ushort* VT = vhT + ((size_t)bh << 16);
    const int nt = 2 * (qb + 1);

    const float* pa[4];
#pragma unroll
    for (int m = 0; m < 4; ++m)
        pa[m] = S + (size_t)(qb * 128 + wr * 64 + m * 16 + l15) * 1024;
    const ushort* pb[2];
#pragma unroll
    for (int n = 0; n < 2; ++n)
        pb[n] = VT + (size_t)(wc * 32 + n * 16 + l15) * 1024;

    f32x4 acc[4][2] = {};
    union U8 { short8 s; ushort u[8]; };

    for (int t = 0; t < nt; ++t) {
        const int off = t * 64 + lg * 8;
        short8 af[2][4], bf[2][2];
#pragma unroll
        for (int kk = 0; kk < 2; ++kk)
#pragma unroll
            for (int m = 0; m < 4; ++m) {
                const float4 x = *(const float4*)&pa[m][off + kk * 32];
                const float4 y = *(const float4*)&pa[m][off + kk * 32 + 4];
                U8 pk;
                pk.u[0] = f2bf(x.x); pk.u[1] = f2bf(x.y);
                pk.u[2] = f2bf(x.z); pk.u[3] = f2bf(x.w);
                pk.u[4] = f2bf(y.x); pk.u[5] = f2bf(y.y);
                pk.u[6] = f2bf(y.z); pk.u[7] = f2bf(y.w);
                af[kk][m] = pk.s;
            }
#pragma unroll
        for (int kk = 0; kk < 2; ++kk)
#pragma unroll
            for (int n = 0; n < 2; ++n)
                bf[kk][n] = *(const short8*)&pb[n][off + kk * 32];
#pragma unroll
        for (int kk = 0; kk < 2; ++kk)
#pragma unroll
            for (int m = 0; m < 4; ++m)
#pragma unroll
                for (int n = 0; n < 2; ++n)
                    acc[m][n] = __builtin_amdgcn_mfma_f32_16x16x32_bf16(af[kk][m], bf[kk][n], acc[m][n], 0, 0, 0);
    }

#pragma unroll
    for (int m = 0; m < 4; ++m)
#pragma unroll
        for (int n = 0; n < 2; ++n)
#pragma unroll
            for (int r = 0; r < 4; ++r) {
                const int row = qb * 128 + wr * 64 + m * 16 + lg * 4 + r;
                const int d = wc * 32 + n * 16 + l15;
                attn[((size_t)(b * 1024 + row)) * 512 + h * 64 + d] = f2bf(acc[m][n][r]);
            }
}

// ---------------------------------------------------------------------------
// Output GEMM: f32 out = attn(bf16) @ Wo^T + bo
// ---------------------------------------------------------------------------
__global__ __launch_bounds__(256)
void gemm_out(const ushort* __restrict__ A, const ushort* __restrict__ B,
              const float* __restrict__ bias, float* __restrict__ out)
{
    __shared__ __align__(16) ushort As[128 * 64];
    __shared__ __align__(16) ushort Bs[128 * 64];
    const int tid = threadIdx.x;
    const int lane = tid & 63;
    const int wave = tid >> 6;
    const int wr = wave >> 1, wc = wave & 1;
    const int bm = blockIdx.x * 128, bn = blockIdx.y * 128;
    const int lrow = lane >> 3;
    const int lcol = (lane & 7) * 8;

    f32x4 acc[4][4] = {};

    for (int k0 = 0; k0 < 512; k0 += 64) {
#pragma unroll
        for (int i = 0; i < 4; ++i) {
            const int c = wave * 4 + i;
            gload16(A + (size_t)(bm + c * 8 + lrow) * 512 + k0 + lcol, &As[c * 512]);
            gload16(B + (size_t)(bn + c * 8 + lrow) * 512 + k0 + lcol, &Bs[c * 512]);
        }
        __syncthreads();
        short8 af[2][4], bf[2][4];
#pragma unroll
        for (int kk = 0; kk < 2; ++kk) {
#pragma unroll
            for (int m = 0; m < 4; ++m)
                af[kk][m] = *(const short8*)&As[(wr * 64 + m * 16 + (lane & 15)) * 64 + kk * 32 + (lane >> 4) * 8];
#pragma unroll
            for (int n = 0; n < 4; ++n)
                bf[kk][n] = *(const short8*)&Bs[(wc * 64 + n * 16 + (lane & 15)) * 64 + kk * 32 + (lane >> 4) * 8];
        }
#pragma unroll
        for (int kk = 0; kk < 2; ++kk)
#pragma unroll
            for (int m = 0; m < 4; ++m)
#pragma unroll
                for (int n = 0; n < 4; ++n)
                    acc[m][n] = __builtin_amdgcn_mfma_f32_16x16x32_bf16(af[kk][m], bf[kk][n], acc[m][n], 0, 0, 0);
        __syncthreads();
    }

#pragma unroll
    for (int m = 0; m < 4; ++m)
#pragma unroll
        for (int n = 0; n < 4; ++n)
#pragma unroll
            for (int r = 0; r < 4; ++r) {
                const int row = bm + wr * 64 + m * 16 + (lane >> 4) * 4 + r;
                const int col = bn + wc * 64 + n * 16 + (lane & 15);
                out[(size_t)row * 512 + col] = acc[m][n][r] + bias[col];
            }
}

// ---------------------------------------------------------------------------
extern "C" void kernel_launch(void* const* d_in, const int* in_sizes, int n_in,
                              void* d_out, int out_size, void* d_ws, size_t ws_size,
                              hipStream_t stream)
{
    const float* q      = (const float*)d_in[0];
    const float* k      = (const float*)d_in[1];
    const float* v      = (const float*)d_in[2];
    const float* Wq     = (const float*)d_in[4];
    const float* bq     = (const float*)d_in[5];
    const float* Wv     = (const float*)d_in[6];
    const float* bv     = (const float*)d_in[7];
    const float* Wo     = (const float*)d_in[8];
    const float* bo     = (const float*)d_in[9];
    const float* gammas = (const float*)d_in[10];

    float* out    = (float*)d_out;                       // [8,1024,512] f32
    float* scores = out + (size_t)PB * PS * PD;          // [64,1024,1024] f32

    char* w = (char*)d_ws;
    ushort* q_bf  = (ushort*)(w);                        // 8 MB
    ushort* k_bf  = (ushort*)(w + (8u  << 20));          // 8 MB
    ushort* v_bf  = (ushort*)(w + (16u << 20));          // 8 MB
    ushort* Wq_bf = (ushort*)(w + (24u << 20));          // 0.5 MB
    ushort* Wv_bf = (ushort*)(w + (24u << 20) + (1u << 19));
    ushort* Wo_bf = (ushort*)(w + (25u << 20));
    ushort* qh    = (ushort*)(w + (26u << 20));          // 8 MB
    ushort* kh    = (ushort*)(w + (34u << 20));          // 8 MB
    ushort* vhT   = (ushort*)(w + (42u << 20));          // 8 MB (plain transpose)
    ushort* attn  = (ushort*)(w + (50u << 20));          // 8 MB

    cast_all<<<13056, 256, 0, stream>>>(q, k, v, Wq, Wv, Wo,
                                        q_bf, k_bf, v_bf, Wq_bf, Wv_bf, Wo_bf);

    proj3<<<dim3(64, 4, 3), 256, 0, stream>>>(q_bf, k_bf, v_bf, Wq_bf, Wv_bf,
                                              bq, bv, qh, kh, vhT);

    qk_mfma<<<4096, 256, 0, stream>>>(qh, kh, scores);
    row_soft<<<4096, 1024, 0, stream>>>(scores, gammas);
    pv_mfma<<<512, 256, 0, stream>>>(scores, vhT, attn);

    gemm_out<<<dim3(64, 4), 256, 0, stream>>>(attn, Wo_bf, bo, out);
}

// Round 9
// 242.299 us; speedup vs baseline: 1.3375x; 1.0331x over previous
//
#include <hip/hip_runtime.h>
#include <hip/hip_bf16.h>

#define PB 8
#define PS 1024
#define PD 512
#define PH 8

typedef __attribute__((ext_vector_type(8))) short short8;
typedef __attribute__((ext_vector_type(4))) float f32x4;

__device__ inline ushort f2bf(float x) {
    union { float f; unsigned u; } c; c.f = x;
    unsigned u = c.u + 0x7fffu + ((c.u >> 16) & 1u);
    return (ushort)(u >> 16);
}
__device__ inline float bf2f(ushort u) {
    union { unsigned u; float f; } c; c.u = (unsigned)u << 16; return c.f;
}

__device__ inline void gload16(const void* g, void* l) {
    __builtin_amdgcn_global_load_lds(
        (const __attribute__((address_space(1))) void*)g,
        (__attribute__((address_space(3))) void*)l, 16, 0, 0);
}

// ---------------------------------------------------------------------------
// One dispatch for all 6 bf16 casts.
// ---------------------------------------------------------------------------
__global__ __launch_bounds__(256)
void cast_all(const float* __restrict__ q, const float* __restrict__ k,
              const float* __restrict__ v, const float* __restrict__ Wq,
              const float* __restrict__ Wv, const float* __restrict__ Wo,
              ushort* __restrict__ q_bf, ushort* __restrict__ k_bf,
              ushort* __restrict__ v_bf, ushort* __restrict__ Wq_bf,
              ushort* __restrict__ Wv_bf, ushort* __restrict__ Wo_bf)
{
    const int bid = blockIdx.x;
    const float* s; ushort* d; int base;
    if      (bid < 4096)  { s = q;  d = q_bf;  base = bid; }
    else if (bid < 8192)  { s = k;  d = k_bf;  base = bid - 4096; }
    else if (bid < 12288) { s = v;  d = v_bf;  base = bid - 8192; }
    else if (bid < 12544) { s = Wq; d = Wq_bf; base = bid - 12288; }
    else if (bid < 12800) { s = Wv; d = Wv_bf; base = bid - 12544; }
    else                  { s = Wo; d = Wo_bf; base = bid - 12800; }
    const int i = base * 256 + threadIdx.x;
    const float4 x = ((const float4*)s)[i];
    ushort4 o;
    o.x = f2bf(x.x); o.y = f2bf(x.y); o.z = f2bf(x.z); o.w = f2bf(x.w);
    ((ushort4*)d)[i] = o;
}

// ---------------------------------------------------------------------------
// All three projections in one dispatch (blockIdx.z = 0:q, 1:k, 2:v).
// z<2 -> bf16 head-split [(b*8+h)*1024+s][64]; z==2 -> plain V^T
// vhT[(b*8+h)*64+d][1024 s].
// ---------------------------------------------------------------------------
__global__ __launch_bounds__(256)
void proj3(const ushort* __restrict__ q_bf, const ushort* __restrict__ k_bf,
           const ushort* __restrict__ v_bf, const ushort* __restrict__ Wq_bf,
           const ushort* __restrict__ Wv_bf, const float* __restrict__ bq,
           const float* __restrict__ bv, ushort* __restrict__ qh,
           ushort* __restrict__ kh, ushort* __restrict__ vhT)
{
    const int z = blockIdx.z;
    const ushort* A = (z == 0) ? q_bf : (z == 1) ? k_bf : v_bf;
    const ushort* B = (z == 2) ? Wv_bf : Wq_bf;
    const float* bias = (z == 2) ? bv : bq;

    __shared__ __align__(16) ushort As[128 * 64];
    __shared__ __align__(16) ushort Bs[128 * 64];
    const int tid = threadIdx.x;
    const int lane = tid & 63;
    const int wave = tid >> 6;
    const int wr = wave >> 1, wc = wave & 1;
    const int bm = blockIdx.x * 128, bn = blockIdx.y * 128;
    const int lrow = lane >> 3;
    const int lcol = (lane & 7) * 8;

    f32x4 acc[4][4] = {};

    for (int k0 = 0; k0 < 512; k0 += 64) {
#pragma unroll
        for (int i = 0; i < 4; ++i) {
            const int c = wave * 4 + i;
            gload16(A + (size_t)(bm + c * 8 + lrow) * 512 + k0 + lcol, &As[c * 512]);
            gload16(B + (size_t)(bn + c * 8 + lrow) * 512 + k0 + lcol, &Bs[c * 512]);
        }
        __syncthreads();
        short8 af[2][4], bf[2][4];
#pragma unroll
        for (int kk = 0; kk < 2; ++kk) {
#pragma unroll
            for (int m = 0; m < 4; ++m)
                af[kk][m] = *(const short8*)&As[(wr * 64 + m * 16 + (lane & 15)) * 64 + kk * 32 + (lane >> 4) * 8];
#pragma unroll
            for (int n = 0; n < 4; ++n)
                bf[kk][n] = *(const short8*)&Bs[(wc * 64 + n * 16 + (lane & 15)) * 64 + kk * 32 + (lane >> 4) * 8];
        }
#pragma unroll
        for (int kk = 0; kk < 2; ++kk)
#pragma unroll
            for (int m = 0; m < 4; ++m)
#pragma unroll
                for (int n = 0; n < 4; ++n)
                    acc[m][n] = __builtin_amdgcn_mfma_f32_16x16x32_bf16(af[kk][m], bf[kk][n], acc[m][n], 0, 0, 0);
        __syncthreads();
    }

#pragma unroll
    for (int m = 0; m < 4; ++m)
#pragma unroll
        for (int n = 0; n < 4; ++n) {
            const int row0 = bm + wr * 64 + m * 16 + (lane >> 4) * 4;
            const int col  = bn + wc * 64 + n * 16 + (lane & 15);
            const int b = row0 >> 10, s0 = row0 & 1023;
            const int h = col >> 6, d = col & 63;
            if (z == 2) {
                ushort4 o;
                o.x = f2bf(acc[m][n][0] + bias[col]);
                o.y = f2bf(acc[m][n][1] + bias[col]);
                o.z = f2bf(acc[m][n][2] + bias[col]);
                o.w = f2bf(acc[m][n][3] + bias[col]);
                *(ushort4*)&vhT[((size_t)((b * 8 + h) * 64 + d)) * 1024 + s0] = o;
            } else {
                ushort* out = z ? kh : qh;
#pragma unroll
                for (int r = 0; r < 4; ++r)
                    out[(((size_t)(b * 8 + h)) * 1024 + s0 + r) * 64 + d] =
                        f2bf(acc[m][n][r] + bias[col]);
            }
        }
}

// ---------------------------------------------------------------------------
// QK^T per (b,h): raw bf16 logits (x0.125) into the first 2KB of each score
// row's 4KB slot. Upper-triangular 128-blocks write f32 zeros (final value).
// Flat grid, bh fastest-varying -> same-bh blocks share an XCD's L2.
// ---------------------------------------------------------------------------
__global__ __launch_bounds__(256)
void qk_mfma(const ushort* __restrict__ qh, const ushort* __restrict__ kh,
             float* __restrict__ scores)
{
    const int d0 = blockIdx.x;           // 0..4095
    const int bh = d0 & 63;
    const int pair = d0 >> 6;            // 0..63
    const int kb = pair & 7, qb = pair >> 3;
    const int tid = threadIdx.x;
    if (kb > qb) {
        // masked region: write final zeros
        float* S = scores + ((size_t)bh << 20);
        const f32x4 z = {};
#pragma unroll
        for (int it = 0; it < 16; ++it) {
            const int f = it * 256 + tid;           // 4096 float4 total
            const int row = f >> 5, c4 = f & 31;
            __builtin_nontemporal_store(z,
                (f32x4*)&S[(size_t)(qb * 128 + row) * 1024 + kb * 128 + c4 * 4]);
        }
        return;
    }
    __shared__ __align__(16) ushort As[128 * 64];
    __shared__ __align__(16) ushort Bs[128 * 64];
    const int lane = tid & 63, wave = tid >> 6;
    const int wr = wave >> 1, wc = wave & 1;
    const ushort* Ab = qh + ((size_t)bh * PS + qb * 128) * 64;
    const ushort* Bb = kh + ((size_t)bh * PS + kb * 128) * 64;

#pragma unroll
    for (int i = 0; i < 4; ++i) {
        const int c = wave * 4 + i;
        gload16(Ab + c * 512 + lane * 8, &As[c * 512]);
        gload16(Bb + c * 512 + lane * 8, &Bs[c * 512]);
    }
    __syncthreads();

    f32x4 acc[4][4] = {};
    short8 af[2][4], bf[2][4];
#pragma unroll
    for (int kk = 0; kk < 2; ++kk) {
#pragma unroll
        for (int m = 0; m < 4; ++m)
            af[kk][m] = *(const short8*)&As[(wr * 64 + m * 16 + (lane & 15)) * 64 + kk * 32 + (lane >> 4) * 8];
#pragma unroll
        for (int n = 0; n < 4; ++n)
            bf[kk][n] = *(const short8*)&Bs[(wc * 64 + n * 16 + (lane & 15)) * 64 + kk * 32 + (lane >> 4) * 8];
    }
#pragma unroll
    for (int kk = 0; kk < 2; ++kk)
#pragma unroll
        for (int m = 0; m < 4; ++m)
#pragma unroll
            for (int n = 0; n < 4; ++n)
                acc[m][n] = __builtin_amdgcn_mfma_f32_16x16x32_bf16(af[kk][m], bf[kk][n], acc[m][n], 0, 0, 0);

    ushort* Sr = (ushort*)(scores + ((size_t)bh << 20));
#pragma unroll
    for (int m = 0; m < 4; ++m)
#pragma unroll
        for (int n = 0; n < 4; ++n)
#pragma unroll
            for (int r = 0; r < 4; ++r) {
                const int row = qb * 128 + wr * 64 + m * 16 + (lane >> 4) * 4 + r;
                const int col = kb * 128 + wc * 64 + n * 16 + (lane & 15);
                Sr[(size_t)row * 2048 + col] = f2bf(acc[m][n][r] * 0.125f);
            }
}

// ---------------------------------------------------------------------------
// Fused row softmax + PV. Block = (bh, 16 rows), 16 waves. Phase 1: streaming
// row pipeline in registers (no LDS). Phase 2: P -> swizzled LDS (1 barrier).
// Phase 3: PV MFMA, waves (kq x 4, nn x 4), V^T read direct from global (L2).
// Phase 4: 16KB RED reduce (1 barrier) -> bf16 attn.
// ---------------------------------------------------------------------------
__global__ __launch_bounds__(1024)
void rowpv2(float* __restrict__ scores, const ushort* __restrict__ vhT,
            const float* __restrict__ gammas, ushort* __restrict__ attn)
{
    const int d0 = blockIdx.x;           // 0..4095
    const int bh = d0 & 63, h = bh & 7;
    const int b = bh >> 3;
    const int rb = d0 >> 6;              // row block 0..63
    const int w = threadIdx.x >> 6;      // wave = row within block
    const int lane = threadIdx.x & 63;
    const int i = rb * 16 + w;
    const int nt = (rb >> 2) + 1;        // 64-col k-tiles for this block
    const int lim = ((i >> 7) + 1) * 128;

    __shared__ __align__(16) ushort P[16 * 1024];   // 32 KB, swizzled
    __shared__ float RED[4][16][68];                // ~17 KB padded

    float* srow = scores + ((size_t)bh << 20) + ((size_t)i << 10);
    const ushort* rraw = (const ushort*)srow;
    const int base = lane * 16;

    union U8 { uint4 v; ushort u[8]; };
    float l[16];
    if (base <= i) {
        U8 a, c2;
        a.v  = *(const uint4*)(rraw + base);
        c2.v = *(const uint4*)(rraw + base + 8);
#pragma unroll
        for (int c = 0; c < 8; ++c) { l[c] = bf2f(a.u[c]); l[c + 8] = bf2f(c2.u[c]); }
#pragma unroll
        for (int c = 0; c < 16; ++c) if (base + c > i) l[c] = -3.0e38f;
    } else {
#pragma unroll
        for (int c = 0; c < 16; ++c) l[c] = -3.0e38f;
    }

    // softmax-1 max
    float m1 = -3.0e38f;
#pragma unroll
    for (int c = 0; c < 16; ++c) m1 = fmaxf(m1, l[c]);
#pragma unroll
    for (int off = 32; off; off >>= 1) m1 = fmaxf(m1, __shfl_xor(m1, off));

    // exp + in-lane inclusive cumsum
    float cum[16];
    float lsum = 0.f;
#pragma unroll
    for (int c = 0; c < 16; ++c) {
        const float e = (base + c <= i) ? __expf(l[c] - m1) : 0.f;
        lsum += e;
        cum[c] = lsum;
    }
    // single 64-lane scan of lane totals
    float incl = lsum;
#pragma unroll
    for (int off = 1; off < 64; off <<= 1) {
        const float y = __shfl_up(incl, off);
        if (lane >= off) incl += y;
    }
    const float excl = incl - lsum;
    const float es = __shfl(incl, 63);
    const float inv_es = 1.0f / es;
    const float gamma = -fabsf(gammas[h]);

    // decay + softmax-2 max
    float m2 = -3.0e38f;
#pragma unroll
    for (int c = 0; c < 16; ++c) {
        if (base + c <= i) {
            const float pe = (float)(i - (base + c));
            const float sfx = fmaxf((es - (excl + cum[c])) * inv_es, 0.f);
            const float dist = sqrtf(sfx * pe);
            const float eff = fmaxf(__expf(gamma * dist), 1e-5f);
            l[c] *= eff;
            m2 = fmaxf(m2, l[c]);
        }
    }
#pragma unroll
    for (int off = 32; off; off >>= 1) m2 = fmaxf(m2, __shfl_xor(m2, off));

    float s2 = 0.f;
#pragma unroll
    for (int c = 0; c < 16; ++c) {
        const float p = (base + c <= i) ? __expf(l[c] - m2) : 0.f;
        l[c] = p; s2 += p;
    }
#pragma unroll
    for (int off = 32; off; off >>= 1) s2 += __shfl_xor(s2, off);
    const float inv2 = 1.0f / s2;
#pragma unroll
    for (int c = 0; c < 16; ++c) l[c] *= inv2;

    // final scores (f32) for cols < lim; cols >= lim already zeroed by qk
    if (base < lim) {
#pragma unroll
        for (int g = 0; g < 4; ++g) {
            f32x4 v;
            v[0] = l[g * 4 + 0]; v[1] = l[g * 4 + 1];
            v[2] = l[g * 4 + 2]; v[3] = l[g * 4 + 3];
            __builtin_nontemporal_store(v, (f32x4*)&srow[base + g * 4]);
        }
    }

    // ---- Phase 2: P -> LDS bf16, XOR-swizzled 16B chunks within 128B groups
    if (base < nt * 64) {
        U8 p0, p1;
#pragma unroll
        for (int c = 0; c < 8; ++c) { p0.u[c] = f2bf(l[c]); p1.u[c] = f2bf(l[c + 8]); }
        const int c0 = 2 * lane, c1 = 2 * lane + 1;
        const int s0 = (c0 & ~7) | ((c0 ^ w) & 7);
        const int s1 = (c1 & ~7) | ((c1 ^ w) & 7);
        *(uint4*)&P[w * 1024 + s0 * 8] = p0.v;
        *(uint4*)&P[w * 1024 + s1 * 8] = p1.v;
    }
    __syncthreads();

    // ---- Phase 3: PV MFMA. wave = (kq, nn); V^T direct from global (L2).
    const int kq = w >> 2, nn = w & 3;
    const int row16 = lane & 15, kg = lane >> 4;
    const ushort* vb = vhT + ((size_t)bh << 16) + (size_t)(nn * 16 + row16) * 1024;
    f32x4 acc = {};
    for (int t = kq; t < nt; t += 4) {
#pragma unroll
        for (int kk = 0; kk < 2; ++kk) {
            const int chunk = t * 8 + ((kk * 4 + kg) ^ (row16 & 7));
            const short8 af = *(const short8*)&P[row16 * 1024 + chunk * 8];
            const short8 bf = *(const short8*)&vb[t * 64 + kk * 32 + kg * 8];
            acc = __builtin_amdgcn_mfma_f32_16x16x32_bf16(af, bf, acc, 0, 0, 0);
        }
    }

    // ---- Phase 4: reduce 4 kq partials, write attn
#pragma unroll
    for (int r = 0; r < 4; ++r)
        RED[kq][kg * 4 + r][nn * 16 + row16] = acc[r];
    __syncthreads();
    const float o = RED[0][w][lane] + RED[1][w][lane] +
                    RED[2][w][lane] + RED[3][w][lane];
    attn[((size_t)(b * 1024 + i)) * 512 + h * 64 + lane] = f2bf(o);
}

// ---------------------------------------------------------------------------
// Output GEMM: f32 out = attn(bf16) @ Wo^T + bo
// ---------------------------------------------------------------------------
__global__ __launch_bounds__(256)
void gemm_out(const ushort* __restrict__ A, const ushort* __restrict__ B,
              const float* __restrict__ bias, float* __restrict__ out)
{
    __shared__ __align__(16) ushort As[128 * 64];
    __shared__ __align__(16) ushort Bs[128 * 64];
    const int tid = threadIdx.x;
    const int lane = tid & 63;
    const int wave = tid >> 6;
    const int wr = wave >> 1, wc = wave & 1;
    const int bm = blockIdx.x * 128, bn = blockIdx.y * 128;
    const int lrow = lane >> 3;
    const int lcol = (lane & 7) * 8;

    f32x4 acc[4][4] = {};

    for (int k0 = 0; k0 < 512; k0 += 64) {
#pragma unroll
        for (int i = 0; i < 4; ++i) {
            const int c = wave * 4 + i;
            gload16(A + (size_t)(bm + c * 8 + lrow) * 512 + k0 + lcol, &As[c * 512]);
            gload16(B + (size_t)(bn + c * 8 + lrow) * 512 + k0 + lcol, &Bs[c * 512]);
        }
        __syncthreads();
        short8 af[2][4], bf[2][4];
#pragma unroll
        for (int kk = 0; kk < 2; ++kk) {
#pragma unroll
            for (int m = 0; m < 4; ++m)
                af[kk][m] = *(const short8*)&As[(wr * 64 + m * 16 + (lane & 15)) * 64 + kk * 32 + (lane >> 4) * 8];
#pragma unroll
            for (int n = 0; n < 4; ++n)
                bf[kk][n] = *(const short8*)&Bs[(wc * 64 + n * 16 + (lane & 15)) * 64 + kk * 32 + (lane >> 4) * 8];
        }
#pragma unroll
        for (int kk = 0; kk < 2; ++kk)
#pragma unroll
            for (int m = 0; m < 4; ++m)
#pragma unroll
                for (int n = 0; n < 4; ++n)
                    acc[m][n] = __builtin_amdgcn_mfma_f32_16x16x32_bf16(af[kk][m], bf[kk][n], acc[m][n], 0, 0, 0);
        __syncthreads();
    }

#pragma unroll
    for (int m = 0; m < 4; ++m)
#pragma unroll
        for (int n = 0; n < 4; ++n)
#pragma unroll
            for (int r = 0; r < 4; ++r) {
                const int row = bm + wr * 64 + m * 16 + (lane >> 4) * 4 + r;
                const int col = bn + wc * 64 + n * 16 + (lane & 15);
                out[(size_t)row * 512 + col] = acc[m][n][r] + bias[col];
            }
}

// ---------------------------------------------------------------------------
extern "C" void kernel_launch(void* const* d_in, const int* in_sizes, int n_in,
                              void* d_out, int out_size, void* d_ws, size_t ws_size,
                              hipStream_t stream)
{
    const float* q      = (const float*)d_in[0];
    const float* k      = (const float*)d_in[1];
    const float* v      = (const float*)d_in[2];
    const float* Wq     = (const float*)d_in[4];
    const float* bq     = (const float*)d_in[5];
    const float* Wv     = (const float*)d_in[6];
    const float* bv     = (const float*)d_in[7];
    const float* Wo     = (const float*)d_in[8];
    const float* bo     = (const float*)d_in[9];
    const float* gammas = (const float*)d_in[10];

    float* out    = (float*)d_out;                       // [8,1024,512] f32
    float* scores = out + (size_t)PB * PS * PD;          // [64,1024,1024] f32

    char* w = (char*)d_ws;
    ushort* q_bf  = (ushort*)(w);                        // 8 MB
    ushort* k_bf  = (ushort*)(w + (8u  << 20));          // 8 MB
    ushort* v_bf  = (ushort*)(w + (16u << 20));          // 8 MB
    ushort* Wq_bf = (ushort*)(w + (24u << 20));          // 0.5 MB
    ushort* Wv_bf = (ushort*)(w + (24u << 20) + (1u << 19));
    ushort* Wo_bf = (ushort*)(w + (25u << 20));
    ushort* qh    = (ushort*)(w + (26u << 20));          // 8 MB
    ushort* kh    = (ushort*)(w + (34u << 20));          // 8 MB
    ushort* vhT   = (ushort*)(w + (42u << 20));          // 8 MB (plain transpose)
    ushort* attn  = (ushort*)(w + (50u << 20));          // 8 MB

    cast_all<<<13056, 256, 0, stream>>>(q, k, v, Wq, Wv, Wo,
                                        q_bf, k_bf, v_bf, Wq_bf, Wv_bf, Wo_bf);

    proj3<<<dim3(64, 4, 3), 256, 0, stream>>>(q_bf, k_bf, v_bf, Wq_bf, Wv_bf,
                                              bq, bv, qh, kh, vhT);

    qk_mfma<<<4096, 256, 0, stream>>>(qh, kh, scores);
    rowpv2<<<4096, 1024, 0, stream>>>(scores, vhT, gammas, attn);

    gemm_out<<<dim3(64, 4), 256, 0, stream>>>(attn, Wo_bf, bo, out);
}

// Round 10
// 241.734 us; speedup vs baseline: 1.3407x; 1.0023x over previous
//
#include <hip/hip_runtime.h>
#include <hip/hip_bf16.h>

#define PB 8
#define PS 1024
#define PD 512
#define PH 8

typedef __attribute__((ext_vector_type(8))) short short8;
typedef __attribute__((ext_vector_type(4))) float f32x4;

__device__ inline ushort f2bf(float x) {
    union { float f; unsigned u; } c; c.f = x;
    unsigned u = c.u + 0x7fffu + ((c.u >> 16) & 1u);
    return (ushort)(u >> 16);
}
__device__ inline float bf2f(ushort u) {
    union { unsigned u; float f; } c; c.u = (unsigned)u << 16; return c.f;
}

__device__ inline void gload16(const void* g, void* l) {
    __builtin_amdgcn_global_load_lds(
        (const __attribute__((address_space(1))) void*)g,
        (__attribute__((address_space(3))) void*)l, 16, 0, 0);
}

// ---------------------------------------------------------------------------
// One dispatch for all 6 bf16 casts.
// ---------------------------------------------------------------------------
__global__ __launch_bounds__(256)
void cast_all(const float* __restrict__ q, const float* __restrict__ k,
              const float* __restrict__ v, const float* __restrict__ Wq,
              const float* __restrict__ Wv, const float* __restrict__ Wo,
              ushort* __restrict__ q_bf, ushort* __restrict__ k_bf,
              ushort* __restrict__ v_bf, ushort* __restrict__ Wq_bf,
              ushort* __restrict__ Wv_bf, ushort* __restrict__ Wo_bf)
{
    const int bid = blockIdx.x;
    const float* s; ushort* d; int base;
    if      (bid < 4096)  { s = q;  d = q_bf;  base = bid; }
    else if (bid < 8192)  { s = k;  d = k_bf;  base = bid - 4096; }
    else if (bid < 12288) { s = v;  d = v_bf;  base = bid - 8192; }
    else if (bid < 12544) { s = Wq; d = Wq_bf; base = bid - 12288; }
    else if (bid < 12800) { s = Wv; d = Wv_bf; base = bid - 12544; }
    else                  { s = Wo; d = Wo_bf; base = bid - 12800; }
    const int i = base * 256 + threadIdx.x;
    const float4 x = ((const float4*)s)[i];
    ushort4 o;
    o.x = f2bf(x.x); o.y = f2bf(x.y); o.z = f2bf(x.z); o.w = f2bf(x.w);
    ((ushort4*)d)[i] = o;
}

// ---------------------------------------------------------------------------
// All three projections in one dispatch (blockIdx.z = 0:q, 1:k, 2:v).
// z<2 -> bf16 head-split [(b*8+h)*1024+s][64]; z==2 -> plain V^T
// vhT[(b*8+h)*64+d][1024 s].
// ---------------------------------------------------------------------------
__global__ __launch_bounds__(256)
void proj3(const ushort* __restrict__ q_bf, const ushort* __restrict__ k_bf,
           const ushort* __restrict__ v_bf, const ushort* __restrict__ Wq_bf,
           const ushort* __restrict__ Wv_bf, const float* __restrict__ bq,
           const float* __restrict__ bv, ushort* __restrict__ qh,
           ushort* __restrict__ kh, ushort* __restrict__ vhT)
{
    const int z = blockIdx.z;
    const ushort* A = (z == 0) ? q_bf : (z == 1) ? k_bf : v_bf;
    const ushort* B = (z == 2) ? Wv_bf : Wq_bf;
    const float* bias = (z == 2) ? bv : bq;

    __shared__ __align__(16) ushort As[128 * 64];
    __shared__ __align__(16) ushort Bs[128 * 64];
    const int tid = threadIdx.x;
    const int lane = tid & 63;
    const int wave = tid >> 6;
    const int wr = wave >> 1, wc = wave & 1;
    const int bm = blockIdx.x * 128, bn = blockIdx.y * 128;
    const int lrow = lane >> 3;
    const int lcol = (lane & 7) * 8;

    f32x4 acc[4][4] = {};

    for (int k0 = 0; k0 < 512; k0 += 64) {
#pragma unroll
        for (int i = 0; i < 4; ++i) {
            const int c = wave * 4 + i;
            gload16(A + (size_t)(bm + c * 8 + lrow) * 512 + k0 + lcol, &As[c * 512]);
            gload16(B + (size_t)(bn + c * 8 + lrow) * 512 + k0 + lcol, &Bs[c * 512]);
        }
        __syncthreads();
        short8 af[2][4], bf[2][4];
#pragma unroll
        for (int kk = 0; kk < 2; ++kk) {
#pragma unroll
            for (int m = 0; m < 4; ++m)
                af[kk][m] = *(const short8*)&As[(wr * 64 + m * 16 + (lane & 15)) * 64 + kk * 32 + (lane >> 4) * 8];
#pragma unroll
            for (int n = 0; n < 4; ++n)
                bf[kk][n] = *(const short8*)&Bs[(wc * 64 + n * 16 + (lane & 15)) * 64 + kk * 32 + (lane >> 4) * 8];
        }
#pragma unroll
        for (int kk = 0; kk < 2; ++kk)
#pragma unroll
            for (int m = 0; m < 4; ++m)
#pragma unroll
                for (int n = 0; n < 4; ++n)
                    acc[m][n] = __builtin_amdgcn_mfma_f32_16x16x32_bf16(af[kk][m], bf[kk][n], acc[m][n], 0, 0, 0);
        __syncthreads();
    }

#pragma unroll
    for (int m = 0; m < 4; ++m)
#pragma unroll
        for (int n = 0; n < 4; ++n) {
            const int row0 = bm + wr * 64 + m * 16 + (lane >> 4) * 4;
            const int col  = bn + wc * 64 + n * 16 + (lane & 15);
            const int b = row0 >> 10, s0 = row0 & 1023;
            const int h = col >> 6, d = col & 63;
            if (z == 2) {
                ushort4 o;
                o.x = f2bf(acc[m][n][0] + bias[col]);
                o.y = f2bf(acc[m][n][1] + bias[col]);
                o.z = f2bf(acc[m][n][2] + bias[col]);
                o.w = f2bf(acc[m][n][3] + bias[col]);
                *(ushort4*)&vhT[((size_t)((b * 8 + h) * 64 + d)) * 1024 + s0] = o;
            } else {
                ushort* out = z ? kh : qh;
#pragma unroll
                for (int r = 0; r < 4; ++r)
                    out[(((size_t)(b * 8 + h)) * 1024 + s0 + r) * 64 + d] =
                        f2bf(acc[m][n][r] + bias[col]);
            }
        }
}

// ---------------------------------------------------------------------------
// QK^T per (b,h): raw bf16 logits (x0.125) into the first 2KB of each score
// row's 4KB slot. Upper-triangular 128-blocks write f32 zeros (final value).
// Flat grid, bh fastest-varying -> same-bh blocks share an XCD's L2.
// ---------------------------------------------------------------------------
__global__ __launch_bounds__(256)
void qk_mfma(const ushort* __restrict__ qh, const ushort* __restrict__ kh,
             float* __restrict__ scores)
{
    const int d0 = blockIdx.x;           // 0..4095
    const int bh = d0 & 63;
    const int pair = d0 >> 6;            // 0..63
    const int kb = pair & 7, qb = pair >> 3;
    const int tid = threadIdx.x;
    if (kb > qb) {
        // masked region: write final zeros
        float* S = scores + ((size_t)bh << 20);
        const f32x4 z = {};
#pragma unroll
        for (int it = 0; it < 16; ++it) {
            const int f = it * 256 + tid;           // 4096 float4 total
            const int row = f >> 5, c4 = f & 31;
            __builtin_nontemporal_store(z,
                (f32x4*)&S[(size_t)(qb * 128 + row) * 1024 + kb * 128 + c4 * 4]);
        }
        return;
    }
    __shared__ __align__(16) ushort As[128 * 64];
    __shared__ __align__(16) ushort Bs[128 * 64];
    const int lane = tid & 63, wave = tid >> 6;
    const int wr = wave >> 1, wc = wave & 1;
    const ushort* Ab = qh + ((size_t)bh * PS + qb * 128) * 64;
    const ushort* Bb = kh + ((size_t)bh * PS + kb * 128) * 64;

#pragma unroll
    for (int i = 0; i < 4; ++i) {
        const int c = wave * 4 + i;
        gload16(Ab + c * 512 + lane * 8, &As[c * 512]);
        gload16(Bb + c * 512 + lane * 8, &Bs[c * 512]);
    }
    __syncthreads();

    f32x4 acc[4][4] = {};
    short8 af[2][4], bf[2][4];
#pragma unroll
    for (int kk = 0; kk < 2; ++kk) {
#pragma unroll
        for (int m = 0; m < 4; ++m)
            af[kk][m] = *(const short8*)&As[(wr * 64 + m * 16 + (lane & 15)) * 64 + kk * 32 + (lane >> 4) * 8];
#pragma unroll
        for (int n = 0; n < 4; ++n)
            bf[kk][n] = *(const short8*)&Bs[(wc * 64 + n * 16 + (lane & 15)) * 64 + kk * 32 + (lane >> 4) * 8];
    }
#pragma unroll
    for (int kk = 0; kk < 2; ++kk)
#pragma unroll
        for (int m = 0; m < 4; ++m)
#pragma unroll
            for (int n = 0; n < 4; ++n)
                acc[m][n] = __builtin_amdgcn_mfma_f32_16x16x32_bf16(af[kk][m], bf[kk][n], acc[m][n], 0, 0, 0);

    ushort* Sr = (ushort*)(scores + ((size_t)bh << 20));
#pragma unroll
    for (int m = 0; m < 4; ++m)
#pragma unroll
        for (int n = 0; n < 4; ++n)
#pragma unroll
            for (int r = 0; r < 4; ++r) {
                const int row = qb * 128 + wr * 64 + m * 16 + (lane >> 4) * 4 + r;
                const int col = kb * 128 + wc * 64 + n * 16 + (lane & 15);
                Sr[(size_t)row * 2048 + col] = f2bf(acc[m][n][r] * 0.125f);
            }
}

// ---------------------------------------------------------------------------
// Fused row softmax + PV, G-adaptive. Block = (bh, 16 rows), 16 waves.
// G = (rb>>4)+1 groups of 4 cols per lane (uniform per block); row covers
// cols [0, 256G) >= nt*64, so the PV read range is always fully written.
// Phase 1: row pipeline in registers. Phase 2: P -> swizzled LDS, barrier.
// Phase 3: f32 score stores (drain under PV) + PV MFMA, V^T direct from L2.
// Phase 4: RED reduce -> bf16 attn.
// ---------------------------------------------------------------------------
__global__ __launch_bounds__(1024)
void rowpv2(float* __restrict__ scores, const ushort* __restrict__ vhT,
            const float* __restrict__ gammas, ushort* __restrict__ attn)
{
    const int d0 = blockIdx.x;           // 0..4095
    const int bh = d0 & 63, h = bh & 7;
    const int b = bh >> 3;
    const int rb = d0 >> 6;              // row block 0..63
    const int w = threadIdx.x >> 6;      // wave = row within block
    const int lane = threadIdx.x & 63;
    const int i = rb * 16 + w;
    const int nt = (rb >> 2) + 1;        // 64-col k-tiles for this block
    const int G = (rb >> 4) + 1;         // 1..4 col-groups of 4 per lane
    const int base = lane * 4 * G;
    const int lim = ((i >> 7) + 1) * 128;

    __shared__ __align__(16) ushort P[16 * 1024];   // 32 KB, swizzled
    __shared__ float RED[4][16][68];                // ~17 KB padded

    float* srow = scores + ((size_t)bh << 20) + ((size_t)i << 10);
    const ushort* rraw = (const ushort*)srow;

    union U4 { uint2 v; ushort u[4]; };
    float l[16];
#pragma unroll
    for (int g = 0; g < 4; ++g) {
        if (g < G) {
            U4 a; a.v = *(const uint2*)(rraw + base + g * 4);
#pragma unroll
            for (int j = 0; j < 4; ++j)
                l[g * 4 + j] = (base + g * 4 + j <= i) ? bf2f(a.u[j]) : -3.0e38f;
        }
    }

    // softmax-1 max
    float m1 = -3.0e38f;
#pragma unroll
    for (int g = 0; g < 4; ++g) if (g < G)
#pragma unroll
        for (int j = 0; j < 4; ++j) m1 = fmaxf(m1, l[g * 4 + j]);
#pragma unroll
    for (int off = 32; off; off >>= 1) m1 = fmaxf(m1, __shfl_xor(m1, off));

    // exp + in-lane inclusive cumsum
    float cum[16];
    float lsum = 0.f;
#pragma unroll
    for (int g = 0; g < 4; ++g) if (g < G)
#pragma unroll
        for (int j = 0; j < 4; ++j) {
            const int c = g * 4 + j;
            const float e = (base + c <= i) ? __expf(l[c] - m1) : 0.f;
            lsum += e;
            cum[c] = lsum;
        }
    // single 64-lane scan of lane totals
    float incl = lsum;
#pragma unroll
    for (int off = 1; off < 64; off <<= 1) {
        const float y = __shfl_up(incl, off);
        if (lane >= off) incl += y;
    }
    const float excl = incl - lsum;
    const float es = __shfl(incl, 63);
    const float inv_es = __builtin_amdgcn_rcpf(es);
    const float gamma = -fabsf(gammas[h]);

    // decay + softmax-2 max
    float m2 = -3.0e38f;
#pragma unroll
    for (int g = 0; g < 4; ++g) if (g < G)
#pragma unroll
        for (int j = 0; j < 4; ++j) {
            const int c = g * 4 + j;
            if (base + c <= i) {
                const float pe = (float)(i - (base + c));
                const float sfx = fmaxf((es - (excl + cum[c])) * inv_es, 0.f);
                const float dist = __builtin_amdgcn_sqrtf(sfx * pe);
                const float eff = fmaxf(__expf(gamma * dist), 1e-5f);
                l[c] *= eff;
                m2 = fmaxf(m2, l[c]);
            }
        }
#pragma unroll
    for (int off = 32; off; off >>= 1) m2 = fmaxf(m2, __shfl_xor(m2, off));

    float s2 = 0.f;
#pragma unroll
    for (int g = 0; g < 4; ++g) if (g < G)
#pragma unroll
        for (int j = 0; j < 4; ++j) {
            const int c = g * 4 + j;
            const float p = (base + c <= i) ? __expf(l[c] - m2) : 0.f;
            l[c] = p; s2 += p;
        }
#pragma unroll
    for (int off = 32; off; off >>= 1) s2 += __shfl_xor(s2, off);
    const float inv2 = __builtin_amdgcn_rcpf(s2);
#pragma unroll
    for (int g = 0; g < 4; ++g) if (g < G)
#pragma unroll
        for (int j = 0; j < 4; ++j) l[g * 4 + j] *= inv2;

    // ---- Phase 2: P -> LDS bf16; logical chunk lc lands at physical
    // (lc&~7)|((lc^w)&7) in 16B units (matches PV read swizzle).
#pragma unroll
    for (int g = 0; g < 4; ++g) {
        if (g < G) {
            U4 p;
#pragma unroll
            for (int j = 0; j < 4; ++j) p.u[j] = f2bf(l[g * 4 + j]);
            const int col = base + g * 4;
            const int lc = col >> 3;
            const int sp = (lc & ~7) | ((lc ^ w) & 7);
            *(uint2*)&P[w * 1024 + sp * 8 + (col & 7)] = p.v;
        }
    }
    __syncthreads();

    // ---- Phase 3a: final f32 score stores (masked cols are exact zeros;
    // cols >= lim already zeroed by qk). Drain under PV compute.
#pragma unroll
    for (int g = 0; g < 4; ++g) {
        if (g < G && base + g * 4 < lim) {
            f32x4 v;
            v[0] = l[g * 4 + 0]; v[1] = l[g * 4 + 1];
            v[2] = l[g * 4 + 2]; v[3] = l[g * 4 + 3];
            __builtin_nontemporal_store(v, (f32x4*)&srow[base + g * 4]);
        }
    }

    // ---- Phase 3b: PV MFMA. wave = (kq, nn); V^T direct from global (L2).
    const int kq = w >> 2, nn = w & 3;
    const int row16 = lane & 15, kg = lane >> 4;
    const ushort* vb = vhT + ((size_t)bh << 16) + (size_t)(nn * 16 + row16) * 1024;
    f32x4 acc = {};
    for (int t = kq; t < nt; t += 4) {
#pragma unroll
        for (int kk = 0; kk < 2; ++kk) {
            const int chunk = t * 8 + ((kk * 4 + kg) ^ (row16 & 7));
            const short8 af = *(const short8*)&P[row16 * 1024 + chunk * 8];
            const short8 bf = *(const short8*)&vb[t * 64 + kk * 32 + kg * 8];
            acc = __builtin_amdgcn_mfma_f32_16x16x32_bf16(af, bf, acc, 0, 0, 0);
        }
    }

    // ---- Phase 4: reduce 4 kq partials, write attn
#pragma unroll
    for (int r = 0; r < 4; ++r)
        RED[kq][kg * 4 + r][nn * 16 + row16] = acc[r];
    __syncthreads();
    const float o = RED[0][w][lane] + RED[1][w][lane] +
                    RED[2][w][lane] + RED[3][w][lane];
    attn[((size_t)(b * 1024 + i)) * 512 + h * 64 + lane] = f2bf(o);
}

// ---------------------------------------------------------------------------
// Output GEMM: f32 out = attn(bf16) @ Wo^T + bo
// ---------------------------------------------------------------------------
__global__ __launch_bounds__(256)
void gemm_out(const ushort* __restrict__ A, const ushort* __restrict__ B,
              const float* __restrict__ bias, float* __restrict__ out)
{
    __shared__ __align__(16) ushort As[128 * 64];
    __shared__ __align__(16) ushort Bs[128 * 64];
    const int tid = threadIdx.x;
    const int lane = tid & 63;
    const int wave = tid >> 6;
    const int wr = wave >> 1, wc = wave & 1;
    const int bm = blockIdx.x * 128, bn = blockIdx.y * 128;
    const int lrow = lane >> 3;
    const int lcol = (lane & 7) * 8;

    f32x4 acc[4][4] = {};

    for (int k0 = 0; k0 < 512; k0 += 64) {
#pragma unroll
        for (int i = 0; i < 4; ++i) {
            const int c = wave * 4 + i;
            gload16(A + (size_t)(bm + c * 8 + lrow) * 512 + k0 + lcol, &As[c * 512]);
            gload16(B + (size_t)(bn + c * 8 + lrow) * 512 + k0 + lcol, &Bs[c * 512]);
        }
        __syncthreads();
        short8 af[2][4], bf[2][4];
#pragma unroll
        for (int kk = 0; kk < 2; ++kk) {
#pragma unroll
            for (int m = 0; m < 4; ++m)
                af[kk][m] = *(const short8*)&As[(wr * 64 + m * 16 + (lane & 15)) * 64 + kk * 32 + (lane >> 4) * 8];
#pragma unroll
            for (int n = 0; n < 4; ++n)
                bf[kk][n] = *(const short8*)&Bs[(wc * 64 + n * 16 + (lane & 15)) * 64 + kk * 32 + (lane >> 4) * 8];
        }
#pragma unroll
        for (int kk = 0; kk < 2; ++kk)
#pragma unroll
            for (int m = 0; m < 4; ++m)
#pragma unroll
                for (int n = 0; n < 4; ++n)
                    acc[m][n] = __builtin_amdgcn_mfma_f32_16x16x32_bf16(af[kk][m], bf[kk][n], acc[m][n], 0, 0, 0);
        __syncthreads();
    }

#pragma unroll
    for (int m = 0; m < 4; ++m)
#pragma unroll
        for (int n = 0; n < 4; ++n)
#pragma unroll
            for (int r = 0; r < 4; ++r) {
                const int row = bm + wr * 64 + m * 16 + (lane >> 4) * 4 + r;
                const int col = bn + wc * 64 + n * 16 + (lane & 15);
                out[(size_t)row * 512 + col] = acc[m][n][r] + bias[col];
            }
}

// ---------------------------------------------------------------------------
extern "C" void kernel_launch(void* const* d_in, const int* in_sizes, int n_in,
                              void* d_out, int out_size, void* d_ws, size_t ws_size,
                              hipStream_t stream)
{
    const float* q      = (const float*)d_in[0];
    const float* k      = (const float*)d_in[1];
    const float* v      = (const float*)d_in[2];
    const float* Wq     = (const float*)d_in[4];
    const float* bq     = (const float*)d_in[5];
    const float* Wv     = (const float*)d_in[6];
    const float* bv     = (const float*)d_in[7];
    const float* Wo     = (const float*)d_in[8];
    const float* bo     = (const float*)d_in[9];
    const float* gammas = (const float*)d_in[10];

    float* out    = (float*)d_out;                       // [8,1024,512] f32
    float* scores = out + (size_t)PB * PS * PD;          // [64,1024,1024] f32

    char* w = (char*)d_ws;
    ushort* q_bf  = (ushort*)(w);                        // 8 MB
    ushort* k_bf  = (ushort*)(w + (8u  << 20));          // 8 MB
    ushort* v_bf  = (ushort*)(w + (16u << 20));          // 8 MB
    ushort* Wq_bf = (ushort*)(w + (24u << 20));          // 0.5 MB
    ushort* Wv_bf = (ushort*)(w + (24u << 20) + (1u << 19));
    ushort* Wo_bf = (ushort*)(w + (25u << 20));
    ushort* qh    = (ushort*)(w + (26u << 20));          // 8 MB
    ushort* kh    = (ushort*)(w + (34u << 20));          // 8 MB
    ushort* vhT   = (ushort*)(w + (42u << 20));          // 8 MB (plain transpose)
    ushort* attn  = (ushort*)(w + (50u << 20));          // 8 MB

    cast_all<<<13056, 256, 0, stream>>>(q, k, v, Wq, Wv, Wo,
                                        q_bf, k_bf, v_bf, Wq_bf, Wv_bf, Wo_bf);

    proj3<<<dim3(64, 4, 3), 256, 0, stream>>>(q_bf, k_bf, v_bf, Wq_bf, Wv_bf,
                                              bq, bv, qh, kh, vhT);

    qk_mfma<<<4096, 256, 0, stream>>>(qh, kh, scores);
    rowpv2<<<4096, 1024, 0, stream>>>(scores, vhT, gammas, attn);

    gemm_out<<<dim3(64, 4), 256, 0, stream>>>(attn, Wo_bf, bo, out);
}

// Round 11
// 238.102 us; speedup vs baseline: 1.3611x; 1.0153x over previous
//
#include <hip/hip_runtime.h>
#include <hip/hip_bf16.h>

#define PB 8
#define PS 1024
#define PD 512
#define PH 8

typedef __attribute__((ext_vector_type(8))) short short8;
typedef __attribute__((ext_vector_type(4))) float f32x4;

__device__ inline ushort f2bf(float x) {
    union { float f; unsigned u; } c; c.f = x;
    unsigned u = c.u + 0x7fffu + ((c.u >> 16) & 1u);
    return (ushort)(u >> 16);
}
__device__ inline float bf2f(ushort u) {
    union { unsigned u; float f; } c; c.u = (unsigned)u << 16; return c.f;
}

__device__ inline void gload16(const void* g, void* l) {
    __builtin_amdgcn_global_load_lds(
        (const __attribute__((address_space(1))) void*)g,
        (__attribute__((address_space(3))) void*)l, 16, 0, 0);
}

// ---------------------------------------------------------------------------
// One dispatch for all 6 bf16 casts.
// ---------------------------------------------------------------------------
__global__ __launch_bounds__(256)
void cast_all(const float* __restrict__ q, const float* __restrict__ k,
              const float* __restrict__ v, const float* __restrict__ Wq,
              const float* __restrict__ Wv, const float* __restrict__ Wo,
              ushort* __restrict__ q_bf, ushort* __restrict__ k_bf,
              ushort* __restrict__ v_bf, ushort* __restrict__ Wq_bf,
              ushort* __restrict__ Wv_bf, ushort* __restrict__ Wo_bf)
{
    const int bid = blockIdx.x;
    const float* s; ushort* d; int base;
    if      (bid < 4096)  { s = q;  d = q_bf;  base = bid; }
    else if (bid < 8192)  { s = k;  d = k_bf;  base = bid - 4096; }
    else if (bid < 12288) { s = v;  d = v_bf;  base = bid - 8192; }
    else if (bid < 12544) { s = Wq; d = Wq_bf; base = bid - 12288; }
    else if (bid < 12800) { s = Wv; d = Wv_bf; base = bid - 12544; }
    else                  { s = Wo; d = Wo_bf; base = bid - 12800; }
    const int i = base * 256 + threadIdx.x;
    const float4 x = ((const float4*)s)[i];
    ushort4 o;
    o.x = f2bf(x.x); o.y = f2bf(x.y); o.z = f2bf(x.z); o.w = f2bf(x.w);
    ((ushort4*)d)[i] = o;
}

// ---------------------------------------------------------------------------
// All three projections in one dispatch (blockIdx.z = 0:q, 1:k, 2:v).
// z<2 -> bf16 head-split [(b*8+h)*1024+s][64]; z==2 -> plain V^T
// vhT[(b*8+h)*64+d][1024 s].
// ---------------------------------------------------------------------------
__global__ __launch_bounds__(256)
void proj3(const ushort* __restrict__ q_bf, const ushort* __restrict__ k_bf,
           const ushort* __restrict__ v_bf, const ushort* __restrict__ Wq_bf,
           const ushort* __restrict__ Wv_bf, const float* __restrict__ bq,
           const float* __restrict__ bv, ushort* __restrict__ qh,
           ushort* __restrict__ kh, ushort* __restrict__ vhT)
{
    const int z = blockIdx.z;
    const ushort* A = (z == 0) ? q_bf : (z == 1) ? k_bf : v_bf;
    const ushort* B = (z == 2) ? Wv_bf : Wq_bf;
    const float* bias = (z == 2) ? bv : bq;

    __shared__ __align__(16) ushort As[128 * 64];
    __shared__ __align__(16) ushort Bs[128 * 64];
    const int tid = threadIdx.x;
    const int lane = tid & 63;
    const int wave = tid >> 6;
    const int wr = wave >> 1, wc = wave & 1;
    const int bm = blockIdx.x * 128, bn = blockIdx.y * 128;
    const int lrow = lane >> 3;
    const int lcol = (lane & 7) * 8;

    f32x4 acc[4][4] = {};

    for (int k0 = 0; k0 < 512; k0 += 64) {
#pragma unroll
        for (int i = 0; i < 4; ++i) {
            const int c = wave * 4 + i;
            gload16(A + (size_t)(bm + c * 8 + lrow) * 512 + k0 + lcol, &As[c * 512]);
            gload16(B + (size_t)(bn + c * 8 + lrow) * 512 + k0 + lcol, &Bs[c * 512]);
        }
        __syncthreads();
        short8 af[2][4], bf[2][4];
#pragma unroll
        for (int kk = 0; kk < 2; ++kk) {
#pragma unroll
            for (int m = 0; m < 4; ++m)
                af[kk][m] = *(const short8*)&As[(wr * 64 + m * 16 + (lane & 15)) * 64 + kk * 32 + (lane >> 4) * 8];
#pragma unroll
            for (int n = 0; n < 4; ++n)
                bf[kk][n] = *(const short8*)&Bs[(wc * 64 + n * 16 + (lane & 15)) * 64 + kk * 32 + (lane >> 4) * 8];
        }
#pragma unroll
        for (int kk = 0; kk < 2; ++kk)
#pragma unroll
            for (int m = 0; m < 4; ++m)
#pragma unroll
                for (int n = 0; n < 4; ++n)
                    acc[m][n] = __builtin_amdgcn_mfma_f32_16x16x32_bf16(af[kk][m], bf[kk][n], acc[m][n], 0, 0, 0);
        __syncthreads();
    }

#pragma unroll
    for (int m = 0; m < 4; ++m)
#pragma unroll
        for (int n = 0; n < 4; ++n) {
            const int row0 = bm + wr * 64 + m * 16 + (lane >> 4) * 4;
            const int col  = bn + wc * 64 + n * 16 + (lane & 15);
            const int b = row0 >> 10, s0 = row0 & 1023;
            const int h = col >> 6, d = col & 63;
            if (z == 2) {
                ushort4 o;
                o.x = f2bf(acc[m][n][0] + bias[col]);
                o.y = f2bf(acc[m][n][1] + bias[col]);
                o.z = f2bf(acc[m][n][2] + bias[col]);
                o.w = f2bf(acc[m][n][3] + bias[col]);
                *(ushort4*)&vhT[((size_t)((b * 8 + h) * 64 + d)) * 1024 + s0] = o;
            } else {
                ushort* out = z ? kh : qh;
#pragma unroll
                for (int r = 0; r < 4; ++r)
                    out[(((size_t)(b * 8 + h)) * 1024 + s0 + r) * 64 + d] =
                        f2bf(acc[m][n][r] + bias[col]);
            }
        }
}

// ---------------------------------------------------------------------------
// QK^T per (b,h): raw bf16 logits (x0.125) into the first 2KB of each score
// row's 4KB slot. Upper-triangular 128-blocks write f32 zeros (final value).
// Flat grid, bh fastest-varying -> same-bh blocks share an XCD's L2.
// ---------------------------------------------------------------------------
__global__ __launch_bounds__(256)
void qk_mfma(const ushort* __restrict__ qh, const ushort* __restrict__ kh,
             float* __restrict__ scores)
{
    const int d0 = blockIdx.x;           // 0..4095
    const int bh = d0 & 63;
    const int pair = d0 >> 6;            // 0..63
    const int kb = pair & 7, qb = pair >> 3;
    const int tid = threadIdx.x;
    if (kb > qb) {
        // masked region: write final zeros
        float* S = scores + ((size_t)bh << 20);
        const f32x4 z = {};
#pragma unroll
        for (int it = 0; it < 16; ++it) {
            const int f = it * 256 + tid;           // 4096 float4 total
            const int row = f >> 5, c4 = f & 31;
            __builtin_nontemporal_store(z,
                (f32x4*)&S[(size_t)(qb * 128 + row) * 1024 + kb * 128 + c4 * 4]);
        }
        return;
    }
    __shared__ __align__(16) ushort As[128 * 64];
    __shared__ __align__(16) ushort Bs[128 * 64];
    const int lane = tid & 63, wave = tid >> 6;
    const int wr = wave >> 1, wc = wave & 1;
    const ushort* Ab = qh + ((size_t)bh * PS + qb * 128) * 64;
    const ushort* Bb = kh + ((size_t)bh * PS + kb * 128) * 64;

#pragma unroll
    for (int i = 0; i < 4; ++i) {
        const int c = wave * 4 + i;
        gload16(Ab + c * 512 + lane * 8, &As[c * 512]);
        gload16(Bb + c * 512 + lane * 8, &Bs[c * 512]);
    }
    __syncthreads();

    f32x4 acc[4][4] = {};
    short8 af[2][4], bf[2][4];
#pragma unroll
    for (int kk = 0; kk < 2; ++kk) {
#pragma unroll
        for (int m = 0; m < 4; ++m)
            af[kk][m] = *(const short8*)&As[(wr * 64 + m * 16 + (lane & 15)) * 64 + kk * 32 + (lane >> 4) * 8];
#pragma unroll
        for (int n = 0; n < 4; ++n)
            bf[kk][n] = *(const short8*)&Bs[(wc * 64 + n * 16 + (lane & 15)) * 64 + kk * 32 + (lane >> 4) * 8];
    }
#pragma unroll
    for (int kk = 0; kk < 2; ++kk)
#pragma unroll
        for (int m = 0; m < 4; ++m)
#pragma unroll
            for (int n = 0; n < 4; ++n)
                acc[m][n] = __builtin_amdgcn_mfma_f32_16x16x32_bf16(af[kk][m], bf[kk][n], acc[m][n], 0, 0, 0);

    ushort* Sr = (ushort*)(scores + ((size_t)bh << 20));
#pragma unroll
    for (int m = 0; m < 4; ++m)
#pragma unroll
        for (int n = 0; n < 4; ++n)
#pragma unroll
            for (int r = 0; r < 4; ++r) {
                const int row = qb * 128 + wr * 64 + m * 16 + (lane >> 4) * 4 + r;
                const int col = kb * 128 + wc * 64 + n * 16 + (lane & 15);
                Sr[(size_t)row * 2048 + col] = f2bf(acc[m][n][r] * 0.125f);
            }
}

// ---------------------------------------------------------------------------
// Fused row softmax + PV, v3: 512 threads = 8 waves = 8 rows per block,
// 8192 blocks -> 4 blocks/CU (20.4 KB LDS). Register-lean row phase:
// no cum[] (running recompute), no second max-reduce (shift M2=max(m1,0),
// exact by softmax shift-invariance). PV: mfma rows 8-15 duplicated/discarded.
// ---------------------------------------------------------------------------
__global__ __launch_bounds__(512, 8)
void rowpv3(float* __restrict__ scores, const ushort* __restrict__ vhT,
            const float* __restrict__ gammas, ushort* __restrict__ attn)
{
    const int d0 = blockIdx.x;           // 0..8191
    const int bh = d0 & 63, h = bh & 7;
    const int b = bh >> 3;
    const int rb = d0 >> 6;              // 8-row block 0..127
    const int w = threadIdx.x >> 6;      // wave = row within block, 0..7
    const int lane = threadIdx.x & 63;
    const int i = rb * 8 + w;
    const int nt = (rb >> 3) + 1;        // 64-col k-tiles for this block
    const int G = (nt + 3) >> 2;         // 1..4 col-groups of 4 per lane
    const int base = lane * 4 * G;       // covers [0, 256G) >= nt*64
    const int lim = ((i >> 7) + 1) * 128;

    __shared__ __align__(16) ushort P[8 * 1024];    // 16 KB, swizzled
    __shared__ float RED[2][8][68];                 // 4.3 KB padded

    float* srow = scores + ((size_t)bh << 20) + ((size_t)i << 10);
    const ushort* rraw = (const ushort*)srow;

    union U4 { uint2 v; ushort u[4]; };
    float l[16];
#pragma unroll
    for (int g = 0; g < 4; ++g) {
        if (g < G) {
            U4 a; a.v = *(const uint2*)(rraw + base + g * 4);
#pragma unroll
            for (int j = 0; j < 4; ++j)
                l[g * 4 + j] = (base + g * 4 + j <= i) ? bf2f(a.u[j]) : -3.0e38f;
        }
    }

    // softmax-1 max
    float m1 = -3.0e38f;
#pragma unroll
    for (int g = 0; g < 4; ++g) if (g < G)
#pragma unroll
        for (int j = 0; j < 4; ++j) m1 = fmaxf(m1, l[g * 4 + j]);
#pragma unroll
    for (int off = 32; off; off >>= 1) m1 = fmaxf(m1, __shfl_xor(m1, off));

    // lane sum of exp (masked cols underflow to 0)
    float lsum = 0.f;
#pragma unroll
    for (int g = 0; g < 4; ++g) if (g < G)
#pragma unroll
        for (int j = 0; j < 4; ++j) lsum += __expf(l[g * 4 + j] - m1);
    // single 64-lane scan of lane totals
    float incl = lsum;
#pragma unroll
    for (int off = 1; off < 64; off <<= 1) {
        const float y = __shfl_up(incl, off);
        if (lane >= off) incl += y;
    }
    const float excl = incl - lsum;
    const float es = __shfl(incl, 63);
    const float inv_es = __builtin_amdgcn_rcpf(es);
    const float gamma = -fabsf(gammas[h]);
    const float M2 = fmaxf(m1, 0.f);     // shift for softmax-2 (exact)

    // decay + softmax-2 numerator (running cumsum recompute)
    float racc = excl;
    float s2 = 0.f;
#pragma unroll
    for (int g = 0; g < 4; ++g) if (g < G)
#pragma unroll
        for (int j = 0; j < 4; ++j) {
            const int c = g * 4 + j;
            if (base + c <= i) {
                racc += __expf(l[c] - m1);
                const float sfxn = fmaxf((es - racc) * inv_es, 0.f);
                const float pe = (float)(i - (base + c));
                const float dist = __builtin_amdgcn_sqrtf(sfxn * pe);
                const float eff = fmaxf(__expf(gamma * dist), 1e-5f);
                const float p = __expf(l[c] * eff - M2);
                l[c] = p; s2 += p;
            } else {
                l[c] = 0.f;
            }
        }
#pragma unroll
    for (int off = 32; off; off >>= 1) s2 += __shfl_xor(s2, off);
    const float inv2 = __builtin_amdgcn_rcpf(s2);
#pragma unroll
    for (int g = 0; g < 4; ++g) if (g < G)
#pragma unroll
        for (int j = 0; j < 4; ++j) l[g * 4 + j] *= inv2;

    // ---- P -> LDS bf16; logical 16B chunk lc -> physical (lc&~7)|((lc^w)&7)
#pragma unroll
    for (int g = 0; g < 4; ++g) {
        if (g < G) {
            U4 p;
#pragma unroll
            for (int j = 0; j < 4; ++j) p.u[j] = f2bf(l[g * 4 + j]);
            const int col = base + g * 4;
            const int lc = col >> 3;
            const int sp = (lc & ~7) | ((lc ^ w) & 7);
            *(uint2*)&P[w * 1024 + sp * 8 + (col & 7)] = p.v;
        }
    }
    __syncthreads();

    // ---- final f32 score stores (drain under PV)
#pragma unroll
    for (int g = 0; g < 4; ++g) {
        if (g < G && base + g * 4 < lim) {
            f32x4 v;
            v[0] = l[g * 4 + 0]; v[1] = l[g * 4 + 1];
            v[2] = l[g * 4 + 2]; v[3] = l[g * 4 + 3];
            __builtin_nontemporal_store(v, (f32x4*)&srow[base + g * 4]);
        }
    }

    // ---- PV MFMA: waves (kq in 0..1, nn in 0..3); A rows 8-15 duplicated,
    // their C rows discarded. V^T direct from global (L2).
    const int kq = w >> 2, nn = w & 3;
    const int row16 = lane & 15, kg = lane >> 4;
    const int arow = lane & 7;           // P row supplied to the A-fragment
    const ushort* vb = vhT + ((size_t)bh << 16) + (size_t)(nn * 16 + row16) * 1024;
    f32x4 acc = {};
    for (int t = kq; t < nt; t += 2) {
#pragma unroll
        for (int kk = 0; kk < 2; ++kk) {
            const int chunk = t * 8 + ((kk * 4 + kg) ^ arow);
            const short8 af = *(const short8*)&P[arow * 1024 + chunk * 8];
            const short8 bf = *(const short8*)&vb[t * 64 + kk * 32 + kg * 8];
            acc = __builtin_amdgcn_mfma_f32_16x16x32_bf16(af, bf, acc, 0, 0, 0);
        }
    }

    // ---- reduce 2 kq partials (C rows 0..7 only), write attn
    if (kg < 2) {
#pragma unroll
        for (int r = 0; r < 4; ++r)
            RED[kq][kg * 4 + r][nn * 16 + row16] = acc[r];
    }
    __syncthreads();
    const float o = RED[0][w][lane] + RED[1][w][lane];
    attn[((size_t)(b * 1024 + i)) * 512 + h * 64 + lane] = f2bf(o);
}

// ---------------------------------------------------------------------------
// Output GEMM: f32 out = attn(bf16) @ Wo^T + bo
// ---------------------------------------------------------------------------
__global__ __launch_bounds__(256)
void gemm_out(const ushort* __restrict__ A, const ushort* __restrict__ B,
              const float* __restrict__ bias, float* __restrict__ out)
{
    __shared__ __align__(16) ushort As[128 * 64];
    __shared__ __align__(16) ushort Bs[128 * 64];
    const int tid = threadIdx.x;
    const int lane = tid & 63;
    const int wave = tid >> 6;
    const int wr = wave >> 1, wc = wave & 1;
    const int bm = blockIdx.x * 128, bn = blockIdx.y * 128;
    const int lrow = lane >> 3;
    const int lcol = (lane & 7) * 8;

    f32x4 acc[4][4] = {};

    for (int k0 = 0; k0 < 512; k0 += 64) {
#pragma unroll
        for (int i = 0; i < 4; ++i) {
            const int c = wave * 4 + i;
            gload16(A + (size_t)(bm + c * 8 + lrow) * 512 + k0 + lcol, &As[c * 512]);
            gload16(B + (size_t)(bn + c * 8 + lrow) * 512 + k0 + lcol, &Bs[c * 512]);
        }
        __syncthreads();
        short8 af[2][4], bf[2][4];
#pragma unroll
        for (int kk = 0; kk < 2; ++kk) {
#pragma unroll
            for (int m = 0; m < 4; ++m)
                af[kk][m] = *(const short8*)&As[(wr * 64 + m * 16 + (lane & 15)) * 64 + kk * 32 + (lane >> 4) * 8];
#pragma unroll
            for (int n = 0; n < 4; ++n)
                bf[kk][n] = *(const short8*)&Bs[(wc * 64 + n * 16 + (lane & 15)) * 64 + kk * 32 + (lane >> 4) * 8];
        }
#pragma unroll
        for (int kk = 0; kk < 2; ++kk)
#pragma unroll
            for (int m = 0; m < 4; ++m)
#pragma unroll
                for (int n = 0; n < 4; ++n)
                    acc[m][n] = __builtin_amdgcn_mfma_f32_16x16x32_bf16(af[kk][m], bf[kk][n], acc[m][n], 0, 0, 0);
        __syncthreads();
    }

#pragma unroll
    for (int m = 0; m < 4; ++m)
#pragma unroll
        for (int n = 0; n < 4; ++n)
#pragma unroll
            for (int r = 0; r < 4; ++r) {
                const int row = bm + wr * 64 + m * 16 + (lane >> 4) * 4 + r;
                const int col = bn + wc * 64 + n * 16 + (lane & 15);
                out[(size_t)row * 512 + col] = acc[m][n][r] + bias[col];
            }
}

// ---------------------------------------------------------------------------
extern "C" void kernel_launch(void* const* d_in, const int* in_sizes, int n_in,
                              void* d_out, int out_size, void* d_ws, size_t ws_size,
                              hipStream_t stream)
{
    const float* q      = (const float*)d_in[0];
    const float* k      = (const float*)d_in[1];
    const float* v      = (const float*)d_in[2];
    const float* Wq     = (const float*)d_in[4];
    const float* bq     = (const float*)d_in[5];
    const float* Wv     = (const float*)d_in[6];
    const float* bv     = (const float*)d_in[7];
    const float* Wo     = (const float*)d_in[8];
    const float* bo     = (const float*)d_in[9];
    const float* gammas = (const float*)d_in[10];

    float* out    = (float*)d_out;                       // [8,1024,512] f32
    float* scores = out + (size_t)PB * PS * PD;          // [64,1024,1024] f32

    char* w = (char*)d_ws;
    ushort* q_bf  = (ushort*)(w);                        // 8 MB
    ushort* k_bf  = (ushort*)(w + (8u  << 20));          // 8 MB
    ushort* v_bf  = (ushort*)(w + (16u << 20));          // 8 MB
    ushort* Wq_bf = (ushort*)(w + (24u << 20));          // 0.5 MB
    ushort* Wv_bf = (ushort*)(w + (24u << 20) + (1u << 19));
    ushort* Wo_bf = (ushort*)(w + (25u << 20));
    ushort* qh    = (ushort*)(w + (26u << 20));          // 8 MB
    ushort* kh    = (ushort*)(w + (34u << 20));          // 8 MB
    ushort* vhT   = (ushort*)(w + (42u << 20));          // 8 MB (plain transpose)
    ushort* attn  = (ushort*)(w + (50u << 20));          // 8 MB

    cast_all<<<13056, 256, 0, stream>>>(q, k, v, Wq, Wv, Wo,
                                        q_bf, k_bf, v_bf, Wq_bf, Wv_bf, Wo_bf);

    proj3<<<dim3(64, 4, 3), 256, 0, stream>>>(q_bf, k_bf, v_bf, Wq_bf, Wv_bf,
                                              bq, bv, qh, kh, vhT);

    qk_mfma<<<4096, 256, 0, stream>>>(qh, kh, scores);
    rowpv3<<<8192, 512, 0, stream>>>(scores, vhT, gammas, attn);

    gemm_out<<<dim3(64, 4), 256, 0, stream>>>(attn, Wo_bf, bo, out);
}

// Round 12
// 236.444 us; speedup vs baseline: 1.3707x; 1.0070x over previous
//
#include <hip/hip_runtime.h>
#include <hip/hip_bf16.h>

#define PB 8
#define PS 1024
#define PD 512
#define PH 8

typedef __attribute__((ext_vector_type(8))) short short8;
typedef __attribute__((ext_vector_type(4))) float f32x4;

__device__ inline ushort f2bf(float x) {
    union { float f; unsigned u; } c; c.f = x;
    unsigned u = c.u + 0x7fffu + ((c.u >> 16) & 1u);
    return (ushort)(u >> 16);
}
__device__ inline float bf2f(ushort u) {
    union { unsigned u; float f; } c; c.u = (unsigned)u << 16; return c.f;
}

__device__ inline void gload16(const void* g, void* l) {
    __builtin_amdgcn_global_load_lds(
        (const __attribute__((address_space(1))) void*)g,
        (__attribute__((address_space(3))) void*)l, 16, 0, 0);
}

// ---------------------------------------------------------------------------
// One dispatch for all 6 bf16 casts.
// ---------------------------------------------------------------------------
__global__ __launch_bounds__(256)
void cast_all(const float* __restrict__ q, const float* __restrict__ k,
              const float* __restrict__ v, const float* __restrict__ Wq,
              const float* __restrict__ Wv, const float* __restrict__ Wo,
              ushort* __restrict__ q_bf, ushort* __restrict__ k_bf,
              ushort* __restrict__ v_bf, ushort* __restrict__ Wq_bf,
              ushort* __restrict__ Wv_bf, ushort* __restrict__ Wo_bf)
{
    const int bid = blockIdx.x;
    const float* s; ushort* d; int base;
    if      (bid < 4096)  { s = q;  d = q_bf;  base = bid; }
    else if (bid < 8192)  { s = k;  d = k_bf;  base = bid - 4096; }
    else if (bid < 12288) { s = v;  d = v_bf;  base = bid - 8192; }
    else if (bid < 12544) { s = Wq; d = Wq_bf; base = bid - 12288; }
    else if (bid < 12800) { s = Wv; d = Wv_bf; base = bid - 12544; }
    else                  { s = Wo; d = Wo_bf; base = bid - 12800; }
    const int i = base * 256 + threadIdx.x;
    const float4 x = ((const float4*)s)[i];
    ushort4 o;
    o.x = f2bf(x.x); o.y = f2bf(x.y); o.z = f2bf(x.z); o.w = f2bf(x.w);
    ((ushort4*)d)[i] = o;
}

// ---------------------------------------------------------------------------
// All three projections in one dispatch (blockIdx.z = 0:q, 1:k, 2:v).
// z<2 -> bf16 head-split [(b*8+h)*1024+s][64]; z==2 -> plain V^T
// vhT[(b*8+h)*64+d][1024 s]. Epilogue: LDS C-bounce -> coalesced 16B stores.
// ---------------------------------------------------------------------------
__global__ __launch_bounds__(256)
void proj3(const ushort* __restrict__ q_bf, const ushort* __restrict__ k_bf,
           const ushort* __restrict__ v_bf, const ushort* __restrict__ Wq_bf,
           const ushort* __restrict__ Wv_bf, const float* __restrict__ bq,
           const float* __restrict__ bv, ushort* __restrict__ qh,
           ushort* __restrict__ kh, ushort* __restrict__ vhT)
{
    const int z = blockIdx.z;
    const ushort* A = (z == 0) ? q_bf : (z == 1) ? k_bf : v_bf;
    const ushort* B = (z == 2) ? Wv_bf : Wq_bf;
    const float* bias = (z == 2) ? bv : bq;

    __shared__ __align__(16) ushort S[128 * 136];   // 34.8 KB
    ushort* As = S;            // [0, 8192)
    ushort* Bs = S + 8192;     // [8192, 16384)
    const int tid = threadIdx.x;
    const int lane = tid & 63;
    const int wave = tid >> 6;
    const int wr = wave >> 1, wc = wave & 1;
    const int bm = blockIdx.x * 128, bn = blockIdx.y * 128;
    const int lrow = lane >> 3;
    const int lcol = (lane & 7) * 8;

    f32x4 acc[4][4] = {};

    for (int k0 = 0; k0 < 512; k0 += 64) {
#pragma unroll
        for (int i = 0; i < 4; ++i) {
            const int c = wave * 4 + i;
            gload16(A + (size_t)(bm + c * 8 + lrow) * 512 + k0 + lcol, &As[c * 512]);
            gload16(B + (size_t)(bn + c * 8 + lrow) * 512 + k0 + lcol, &Bs[c * 512]);
        }
        __syncthreads();
        short8 af[2][4], bf[2][4];
#pragma unroll
        for (int kk = 0; kk < 2; ++kk) {
#pragma unroll
            for (int m = 0; m < 4; ++m)
                af[kk][m] = *(const short8*)&As[(wr * 64 + m * 16 + (lane & 15)) * 64 + kk * 32 + (lane >> 4) * 8];
#pragma unroll
            for (int n = 0; n < 4; ++n)
                bf[kk][n] = *(const short8*)&Bs[(wc * 64 + n * 16 + (lane & 15)) * 64 + kk * 32 + (lane >> 4) * 8];
        }
#pragma unroll
        for (int kk = 0; kk < 2; ++kk)
#pragma unroll
            for (int m = 0; m < 4; ++m)
#pragma unroll
                for (int n = 0; n < 4; ++n)
                    acc[m][n] = __builtin_amdgcn_mfma_f32_16x16x32_bf16(af[kk][m], bf[kk][n], acc[m][n], 0, 0, 0);
        __syncthreads();
    }

    // ---- stage C into LDS (bf16, stride 136) ----
    if (z == 2) {
        // transposed: S[col*136 + row] so vhT streams contiguous in s
#pragma unroll
        for (int m = 0; m < 4; ++m)
#pragma unroll
            for (int n = 0; n < 4; ++n) {
                const int r0 = wr * 64 + m * 16 + (lane >> 4) * 4;
                const int cl = wc * 64 + n * 16 + (lane & 15);
                const float bi = bias[bn + cl];
                ushort4 o;
                o.x = f2bf(acc[m][n][0] + bi);
                o.y = f2bf(acc[m][n][1] + bi);
                o.z = f2bf(acc[m][n][2] + bi);
                o.w = f2bf(acc[m][n][3] + bi);
                *(ushort4*)&S[cl * 136 + r0] = o;
            }
    } else {
#pragma unroll
        for (int m = 0; m < 4; ++m)
#pragma unroll
            for (int n = 0; n < 4; ++n) {
                const int r0 = wr * 64 + m * 16 + (lane >> 4) * 4;
                const int cl = wc * 64 + n * 16 + (lane & 15);
                const float bi = bias[bn + cl];
#pragma unroll
                for (int r = 0; r < 4; ++r)
                    S[(r0 + r) * 136 + cl] = f2bf(acc[m][n][r] + bi);
            }
    }
    __syncthreads();

    // ---- coalesced 16B stores: 2048 chunks, 8 per thread ----
    const int b = bm >> 10, sbase = bm & 1023;
    if (z == 2) {
#pragma unroll
        for (int it = 0; it < 8; ++it) {
            const int c = it * 256 + tid;
            const int dloc = c >> 4, seg = c & 15;      // d-local, s-chunk
            const int h = (bn >> 6) + (dloc >> 6), d = dloc & 63;
            const uint4 v4 = *(const uint4*)&S[dloc * 136 + seg * 8];
            *(uint4*)&vhT[((size_t)((b * 8 + h) * 64 + d)) * 1024 + sbase + seg * 8] = v4;
        }
    } else {
        ushort* out = z ? kh : qh;
#pragma unroll
        for (int it = 0; it < 8; ++it) {
            const int c = it * 256 + tid;
            const int row = c >> 4, seg = c & 15;       // s-local, col-chunk
            const int h = (bn >> 6) + (seg >> 3), d8 = (seg & 7) * 8;
            const uint4 v4 = *(const uint4*)&S[row * 136 + seg * 8];
            *(uint4*)&out[(((size_t)(b * 8 + h)) * 1024 + sbase + row) * 64 + d8] = v4;
        }
    }
}

// ---------------------------------------------------------------------------
// QK^T per (b,h): raw bf16 logits (x0.125) into the first 2KB of each score
// row's 4KB slot, via LDS C-bounce -> coalesced 16B stores. Upper-triangular
// 128-blocks write f32 zeros. Flat grid, bh fastest-varying (XCD L2 share).
// ---------------------------------------------------------------------------
__global__ __launch_bounds__(256)
void qk_mfma(const ushort* __restrict__ qh, const ushort* __restrict__ kh,
             float* __restrict__ scores)
{
    const int d0 = blockIdx.x;           // 0..4095
    const int bh = d0 & 63;
    const int pair = d0 >> 6;            // 0..63
    const int kb = pair & 7, qb = pair >> 3;
    const int tid = threadIdx.x;
    if (kb > qb) {
        // masked region: write final zeros
        float* S = scores + ((size_t)bh << 20);
        const f32x4 z = {};
#pragma unroll
        for (int it = 0; it < 16; ++it) {
            const int f = it * 256 + tid;           // 4096 float4 total
            const int row = f >> 5, c4 = f & 31;
            __builtin_nontemporal_store(z,
                (f32x4*)&S[(size_t)(qb * 128 + row) * 1024 + kb * 128 + c4 * 4]);
        }
        return;
    }
    __shared__ __align__(16) ushort S[128 * 136];   // 34.8 KB
    ushort* As = S;
    ushort* Bs = S + 8192;
    const int lane = tid & 63, wave = tid >> 6;
    const int wr = wave >> 1, wc = wave & 1;
    const ushort* Ab = qh + ((size_t)bh * PS + qb * 128) * 64;
    const ushort* Bb = kh + ((size_t)bh * PS + kb * 128) * 64;

#pragma unroll
    for (int i = 0; i < 4; ++i) {
        const int c = wave * 4 + i;
        gload16(Ab + c * 512 + lane * 8, &As[c * 512]);
        gload16(Bb + c * 512 + lane * 8, &Bs[c * 512]);
    }
    __syncthreads();

    f32x4 acc[4][4] = {};
    short8 af[2][4], bf[2][4];
#pragma unroll
    for (int kk = 0; kk < 2; ++kk) {
#pragma unroll
        for (int m = 0; m < 4; ++m)
            af[kk][m] = *(const short8*)&As[(wr * 64 + m * 16 + (lane & 15)) * 64 + kk * 32 + (lane >> 4) * 8];
#pragma unroll
        for (int n = 0; n < 4; ++n)
            bf[kk][n] = *(const short8*)&Bs[(wc * 64 + n * 16 + (lane & 15)) * 64 + kk * 32 + (lane >> 4) * 8];
    }
#pragma unroll
    for (int kk = 0; kk < 2; ++kk)
#pragma unroll
        for (int m = 0; m < 4; ++m)
#pragma unroll
            for (int n = 0; n < 4; ++n)
                acc[m][n] = __builtin_amdgcn_mfma_f32_16x16x32_bf16(af[kk][m], bf[kk][n], acc[m][n], 0, 0, 0);

    __syncthreads();   // all fragment reads done before C overwrites S

    // ---- stage C bf16 (x0.125) into LDS, stride 136 ----
#pragma unroll
    for (int m = 0; m < 4; ++m)
#pragma unroll
        for (int n = 0; n < 4; ++n) {
            const int r0 = wr * 64 + m * 16 + (lane >> 4) * 4;
            const int cl = wc * 64 + n * 16 + (lane & 15);
#pragma unroll
            for (int r = 0; r < 4; ++r)
                S[(r0 + r) * 136 + cl] = f2bf(acc[m][n][r] * 0.125f);
        }
    __syncthreads();

    // ---- coalesced 16B stores of the raw tile ----
    ushort* Sr = (ushort*)(scores + ((size_t)bh << 20));
#pragma unroll
    for (int it = 0; it < 8; ++it) {
        const int c = it * 256 + tid;
        const int row = c >> 4, seg = c & 15;
        const uint4 v4 = *(const uint4*)&S[row * 136 + seg * 8];
        *(uint4*)&Sr[(size_t)(qb * 128 + row) * 2048 + kb * 128 + seg * 8] = v4;
    }
}

// ---------------------------------------------------------------------------
// Fused row softmax + PV, v3: 512 threads = 8 waves = 8 rows per block.
// (unchanged from round 11)
// ---------------------------------------------------------------------------
__global__ __launch_bounds__(512, 8)
void rowpv3(float* __restrict__ scores, const ushort* __restrict__ vhT,
            const float* __restrict__ gammas, ushort* __restrict__ attn)
{
    const int d0 = blockIdx.x;           // 0..8191
    const int bh = d0 & 63, h = bh & 7;
    const int b = bh >> 3;
    const int rb = d0 >> 6;              // 8-row block 0..127
    const int w = threadIdx.x >> 6;      // wave = row within block, 0..7
    const int lane = threadIdx.x & 63;
    const int i = rb * 8 + w;
    const int nt = (rb >> 3) + 1;        // 64-col k-tiles for this block
    const int G = (nt + 3) >> 2;         // 1..4 col-groups of 4 per lane
    const int base = lane * 4 * G;       // covers [0, 256G) >= nt*64
    const int lim = ((i >> 7) + 1) * 128;

    __shared__ __align__(16) ushort P[8 * 1024];    // 16 KB, swizzled
    __shared__ float RED[2][8][68];                 // 4.3 KB padded

    float* srow = scores + ((size_t)bh << 20) + ((size_t)i << 10);
    const ushort* rraw = (const ushort*)srow;

    union U4 { uint2 v; ushort u[4]; };
    float l[16];
#pragma unroll
    for (int g = 0; g < 4; ++g) {
        if (g < G) {
            U4 a; a.v = *(const uint2*)(rraw + base + g * 4);
#pragma unroll
            for (int j = 0; j < 4; ++j)
                l[g * 4 + j] = (base + g * 4 + j <= i) ? bf2f(a.u[j]) : -3.0e38f;
        }
    }

    // softmax-1 max
    float m1 = -3.0e38f;
#pragma unroll
    for (int g = 0; g < 4; ++g) if (g < G)
#pragma unroll
        for (int j = 0; j < 4; ++j) m1 = fmaxf(m1, l[g * 4 + j]);
#pragma unroll
    for (int off = 32; off; off >>= 1) m1 = fmaxf(m1, __shfl_xor(m1, off));

    // lane sum of exp (masked cols underflow to 0)
    float lsum = 0.f;
#pragma unroll
    for (int g = 0; g < 4; ++g) if (g < G)
#pragma unroll
        for (int j = 0; j < 4; ++j) lsum += __expf(l[g * 4 + j] - m1);
    // single 64-lane scan of lane totals
    float incl = lsum;
#pragma unroll
    for (int off = 1; off < 64; off <<= 1) {
        const float y = __shfl_up(incl, off);
        if (lane >= off) incl += y;
    }
    const float excl = incl - lsum;
    const float es = __shfl(incl, 63);
    const float inv_es = __builtin_amdgcn_rcpf(es);
    const float gamma = -fabsf(gammas[h]);
    const float M2 = fmaxf(m1, 0.f);     // shift for softmax-2 (exact)

    // decay + softmax-2 numerator (running cumsum recompute)
    float racc = excl;
    float s2 = 0.f;
#pragma unroll
    for (int g = 0; g < 4; ++g) if (g < G)
#pragma unroll
        for (int j = 0; j < 4; ++j) {
            const int c = g * 4 + j;
            if (base + c <= i) {
                racc += __expf(l[c] - m1);
                const float sfxn = fmaxf((es - racc) * inv_es, 0.f);
                const float pe = (float)(i - (base + c));
                const float dist = __builtin_amdgcn_sqrtf(sfxn * pe);
                const float eff = fmaxf(__expf(gamma * dist), 1e-5f);
                const float p = __expf(l[c] * eff - M2);
                l[c] = p; s2 += p;
            } else {
                l[c] = 0.f;
            }
        }
#pragma unroll
    for (int off = 32; off; off >>= 1) s2 += __shfl_xor(s2, off);
    const float inv2 = __builtin_amdgcn_rcpf(s2);
#pragma unroll
    for (int g = 0; g < 4; ++g) if (g < G)
#pragma unroll
        for (int j = 0; j < 4; ++j) l[g * 4 + j] *= inv2;

    // ---- P -> LDS bf16; logical 16B chunk lc -> physical (lc&~7)|((lc^w)&7)
#pragma unroll
    for (int g = 0; g < 4; ++g) {
        if (g < G) {
            U4 p;
#pragma unroll
            for (int j = 0; j < 4; ++j) p.u[j] = f2bf(l[g * 4 + j]);
            const int col = base + g * 4;
            const int lc = col >> 3;
            const int sp = (lc & ~7) | ((lc ^ w) & 7);
            *(uint2*)&P[w * 1024 + sp * 8 + (col & 7)] = p.v;
        }
    }
    __syncthreads();

    // ---- final f32 score stores (drain under PV)
#pragma unroll
    for (int g = 0; g < 4; ++g) {
        if (g < G && base + g * 4 < lim) {
            f32x4 v;
            v[0] = l[g * 4 + 0]; v[1] = l[g * 4 + 1];
            v[2] = l[g * 4 + 2]; v[3] = l[g * 4 + 3];
            __builtin_nontemporal_store(v, (f32x4*)&srow[base + g * 4]);
        }
    }

    // ---- PV MFMA: waves (kq in 0..1, nn in 0..3); A rows 8-15 duplicated,
    // their C rows discarded. V^T direct from global (L2).
    const int kq = w >> 2, nn = w & 3;
    const int row16 = lane & 15, kg = lane >> 4;
    const int arow = lane & 7;           // P row supplied to the A-fragment
    const ushort* vb = vhT + ((size_t)bh << 16) + (size_t)(nn * 16 + row16) * 1024;
    f32x4 acc = {};
    for (int t = kq; t < nt; t += 2) {
#pragma unroll
        for (int kk = 0; kk < 2; ++kk) {
            const int chunk = t * 8 + ((kk * 4 + kg) ^ arow);
            const short8 af = *(const short8*)&P[arow * 1024 + chunk * 8];
            const short8 bf = *(const short8*)&vb[t * 64 + kk * 32 + kg * 8];
            acc = __builtin_amdgcn_mfma_f32_16x16x32_bf16(af, bf, acc, 0, 0, 0);
        }
    }

    // ---- reduce 2 kq partials (C rows 0..7 only), write attn
    if (kg < 2) {
#pragma unroll
        for (int r = 0; r < 4; ++r)
            RED[kq][kg * 4 + r][nn * 16 + row16] = acc[r];
    }
    __syncthreads();
    const float o = RED[0][w][lane] + RED[1][w][lane];
    attn[((size_t)(b * 1024 + i)) * 512 + h * 64 + lane] = f2bf(o);
}

// ---------------------------------------------------------------------------
// Output GEMM: f32 out = attn(bf16) @ Wo^T + bo
// ---------------------------------------------------------------------------
__global__ __launch_bounds__(256)
void gemm_out(const ushort* __restrict__ A, const ushort* __restrict__ B,
              const float* __restrict__ bias, float* __restrict__ out)
{
    __shared__ __align__(16) ushort As[128 * 64];
    __shared__ __align__(16) ushort Bs[128 * 64];
    const int tid = threadIdx.x;
    const int lane = tid & 63;
    const int wave = tid >> 6;
    const int wr = wave >> 1, wc = wave & 1;
    const int bm = blockIdx.x * 128, bn = blockIdx.y * 128;
    const int lrow = lane >> 3;
    const int lcol = (lane & 7) * 8;

    f32x4 acc[4][4] = {};

    for (int k0 = 0; k0 < 512; k0 += 64) {
#pragma unroll
        for (int i = 0; i < 4; ++i) {
            const int c = wave * 4 + i;
            gload16(A + (size_t)(bm + c * 8 + lrow) * 512 + k0 + lcol, &As[c * 512]);
            gload16(B + (size_t)(bn + c * 8 + lrow) * 512 + k0 + lcol, &Bs[c * 512]);
        }
        __syncthreads();
        short8 af[2][4], bf[2][4];
#pragma unroll
        for (int kk = 0; kk < 2; ++kk) {
#pragma unroll
            for (int m = 0; m < 4; ++m)
                af[kk][m] = *(const short8*)&As[(wr * 64 + m * 16 + (lane & 15)) * 64 + kk * 32 + (lane >> 4) * 8];
#pragma unroll
            for (int n = 0; n < 4; ++n)
                bf[kk][n] = *(const short8*)&Bs[(wc * 64 + n * 16 + (lane & 15)) * 64 + kk * 32 + (lane >> 4) * 8];
        }
#pragma unroll
        for (int kk = 0; kk < 2; ++kk)
#pragma unroll
            for (int m = 0; m < 4; ++m)
#pragma unroll
                for (int n = 0; n < 4; ++n)
                    acc[m][n] = __builtin_amdgcn_mfma_f32_16x16x32_bf16(af[kk][m], bf[kk][n], acc[m][n], 0, 0, 0);
        __syncthreads();
    }

#pragma unroll
    for (int m = 0; m < 4; ++m)
#pragma unroll
        for (int n = 0; n < 4; ++n)
#pragma unroll
            for (int r = 0; r < 4; ++r) {
                const int row = bm + wr * 64 + m * 16 + (lane >> 4) * 4 + r;
                const int col = bn + wc * 64 + n * 16 + (lane & 15);
                out[(size_t)row * 512 + col] = acc[m][n][r] + bias[col];
            }
}

// ---------------------------------------------------------------------------
extern "C" void kernel_launch(void* const* d_in, const int* in_sizes, int n_in,
                              void* d_out, int out_size, void* d_ws, size_t ws_size,
                              hipStream_t stream)
{
    const float* q      = (const float*)d_in[0];
    const float* k      = (const float*)d_in[1];
    const float* v      = (const float*)d_in[2];
    const float* Wq     = (const float*)d_in[4];
    const float* bq     = (const float*)d_in[5];
    const float* Wv     = (const float*)d_in[6];
    const float* bv     = (const float*)d_in[7];
    const float* Wo     = (const float*)d_in[8];
    const float* bo     = (const float*)d_in[9];
    const float* gammas = (const float*)d_in[10];

    float* out    = (float*)d_out;                       // [8,1024,512] f32
    float* scores = out + (size_t)PB * PS * PD;          // [64,1024,1024] f32

    char* w = (char*)d_ws;
    ushort* q_bf  = (ushort*)(w);                        // 8 MB
    ushort* k_bf  = (ushort*)(w + (8u  << 20));          // 8 MB
    ushort* v_bf  = (ushort*)(w + (16u << 20));          // 8 MB
    ushort* Wq_bf = (ushort*)(w + (24u << 20));          // 0.5 MB
    ushort* Wv_bf = (ushort*)(w + (24u << 20) + (1u << 19));
    ushort* Wo_bf = (ushort*)(w + (25u << 20));
    ushort* qh    = (ushort*)(w + (26u << 20));          // 8 MB
    ushort* kh    = (ushort*)(w + (34u << 20));          // 8 MB
    ushort* vhT   = (ushort*)(w + (42u << 20));          // 8 MB (plain transpose)
    ushort* attn  = (ushort*)(w + (50u << 20));          // 8 MB

    cast_all<<<13056, 256, 0, stream>>>(q, k, v, Wq, Wv, Wo,
                                        q_bf, k_bf, v_bf, Wq_bf, Wv_bf, Wo_bf);

    proj3<<<dim3(64, 4, 3), 256, 0, stream>>>(q_bf, k_bf, v_bf, Wq_bf, Wv_bf,
                                              bq, bv, qh, kh, vhT);

    qk_mfma<<<4096, 256, 0, stream>>>(qh, kh, scores);
    rowpv3<<<8192, 512, 0, stream>>>(scores, vhT, gammas, attn);

    gemm_out<<<dim3(64, 4), 256, 0, stream>>>(attn, Wo_bf, bo, out);
}

// Round 13
// 202.412 us; speedup vs baseline: 1.6011x; 1.1681x over previous
//
#include <hip/hip_runtime.h>
#include <hip/hip_bf16.h>

#define PB 8
#define PS 1024
#define PD 512
#define PH 8

typedef __attribute__((ext_vector_type(8))) short short8;
typedef __attribute__((ext_vector_type(4))) float f32x4;

__device__ inline ushort f2bf(float x) {
    union { float f; unsigned u; } c; c.f = x;
    unsigned u = c.u + 0x7fffu + ((c.u >> 16) & 1u);
    return (ushort)(u >> 16);
}
__device__ inline float bf2f(ushort u) {
    union { unsigned u; float f; } c; c.u = (unsigned)u << 16; return c.f;
}

__device__ inline void gload16(const void* g, void* l) {
    __builtin_amdgcn_global_load_lds(
        (const __attribute__((address_space(1))) void*)g,
        (__attribute__((address_space(3))) void*)l, 16, 0, 0);
}

// ---------------------------------------------------------------------------
// One dispatch for all 6 bf16 casts.
// ---------------------------------------------------------------------------
__global__ __launch_bounds__(256)
void cast_all(const float* __restrict__ q, const float* __restrict__ k,
              const float* __restrict__ v, const float* __restrict__ Wq,
              const float* __restrict__ Wv, const float* __restrict__ Wo,
              ushort* __restrict__ q_bf, ushort* __restrict__ k_bf,
              ushort* __restrict__ v_bf, ushort* __restrict__ Wq_bf,
              ushort* __restrict__ Wv_bf, ushort* __restrict__ Wo_bf)
{
    const int bid = blockIdx.x;
    const float* s; ushort* d; int base;
    if      (bid < 4096)  { s = q;  d = q_bf;  base = bid; }
    else if (bid < 8192)  { s = k;  d = k_bf;  base = bid - 4096; }
    else if (bid < 12288) { s = v;  d = v_bf;  base = bid - 8192; }
    else if (bid < 12544) { s = Wq; d = Wq_bf; base = bid - 12288; }
    else if (bid < 12800) { s = Wv; d = Wv_bf; base = bid - 12544; }
    else                  { s = Wo; d = Wo_bf; base = bid - 12800; }
    const int i = base * 256 + threadIdx.x;
    const float4 x = ((const float4*)s)[i];
    ushort4 o;
    o.x = f2bf(x.x); o.y = f2bf(x.y); o.z = f2bf(x.z); o.w = f2bf(x.w);
    ((ushort4*)d)[i] = o;
}

// ---------------------------------------------------------------------------
// All three projections in one dispatch (blockIdx.z = 0:q, 1:k, 2:v).
// z<2 -> bf16 head-split [(b*8+h)*1024+s][64]; z==2 -> plain V^T
// vhT[(b*8+h)*64+d][1024 s]. Epilogue: LDS C-bounce -> coalesced 16B stores.
// ---------------------------------------------------------------------------
__global__ __launch_bounds__(256)
void proj3(const ushort* __restrict__ q_bf, const ushort* __restrict__ k_bf,
           const ushort* __restrict__ v_bf, const ushort* __restrict__ Wq_bf,
           const ushort* __restrict__ Wv_bf, const float* __restrict__ bq,
           const float* __restrict__ bv, ushort* __restrict__ qh,
           ushort* __restrict__ kh, ushort* __restrict__ vhT)
{
    const int z = blockIdx.z;
    const ushort* A = (z == 0) ? q_bf : (z == 1) ? k_bf : v_bf;
    const ushort* B = (z == 2) ? Wv_bf : Wq_bf;
    const float* bias = (z == 2) ? bv : bq;

    __shared__ __align__(16) ushort S[128 * 136];   // 34.8 KB
    ushort* As = S;            // [0, 8192)
    ushort* Bs = S + 8192;     // [8192, 16384)
    const int tid = threadIdx.x;
    const int lane = tid & 63;
    const int wave = tid >> 6;
    const int wr = wave >> 1, wc = wave & 1;
    const int bm = blockIdx.x * 128, bn = blockIdx.y * 128;
    const int lrow = lane >> 3;
    const int lcol = (lane & 7) * 8;

    f32x4 acc[4][4] = {};

    for (int k0 = 0; k0 < 512; k0 += 64) {
#pragma unroll
        for (int i = 0; i < 4; ++i) {
            const int c = wave * 4 + i;
            gload16(A + (size_t)(bm + c * 8 + lrow) * 512 + k0 + lcol, &As[c * 512]);
            gload16(B + (size_t)(bn + c * 8 + lrow) * 512 + k0 + lcol, &Bs[c * 512]);
        }
        __syncthreads();
        short8 af[2][4], bf[2][4];
#pragma unroll
        for (int kk = 0; kk < 2; ++kk) {
#pragma unroll
            for (int m = 0; m < 4; ++m)
                af[kk][m] = *(const short8*)&As[(wr * 64 + m * 16 + (lane & 15)) * 64 + kk * 32 + (lane >> 4) * 8];
#pragma unroll
            for (int n = 0; n < 4; ++n)
                bf[kk][n] = *(const short8*)&Bs[(wc * 64 + n * 16 + (lane & 15)) * 64 + kk * 32 + (lane >> 4) * 8];
        }
#pragma unroll
        for (int kk = 0; kk < 2; ++kk)
#pragma unroll
            for (int m = 0; m < 4; ++m)
#pragma unroll
                for (int n = 0; n < 4; ++n)
                    acc[m][n] = __builtin_amdgcn_mfma_f32_16x16x32_bf16(af[kk][m], bf[kk][n], acc[m][n], 0, 0, 0);
        __syncthreads();
    }

    // ---- stage C into LDS (bf16, stride 136) ----
    if (z == 2) {
        // transposed: S[col*136 + row] so vhT streams contiguous in s
#pragma unroll
        for (int m = 0; m < 4; ++m)
#pragma unroll
            for (int n = 0; n < 4; ++n) {
                const int r0 = wr * 64 + m * 16 + (lane >> 4) * 4;
                const int cl = wc * 64 + n * 16 + (lane & 15);
                const float bi = bias[bn + cl];
                ushort4 o;
                o.x = f2bf(acc[m][n][0] + bi);
                o.y = f2bf(acc[m][n][1] + bi);
                o.z = f2bf(acc[m][n][2] + bi);
                o.w = f2bf(acc[m][n][3] + bi);
                *(ushort4*)&S[cl * 136 + r0] = o;
            }
    } else {
#pragma unroll
        for (int m = 0; m < 4; ++m)
#pragma unroll
            for (int n = 0; n < 4; ++n) {
                const int r0 = wr * 64 + m * 16 + (lane >> 4) * 4;
                const int cl = wc * 64 + n * 16 + (lane & 15);
                const float bi = bias[bn + cl];
#pragma unroll
                for (int r = 0; r < 4; ++r)
                    S[(r0 + r) * 136 + cl] = f2bf(acc[m][n][r] + bi);
            }
    }
    __syncthreads();

    // ---- coalesced 16B stores: 2048 chunks, 8 per thread ----
    const int b = bm >> 10, sbase = bm & 1023;
    if (z == 2) {
#pragma unroll
        for (int it = 0; it < 8; ++it) {
            const int c = it * 256 + tid;
            const int dloc = c >> 4, seg = c & 15;      // d-local, s-chunk
            const int h = (bn >> 6) + (dloc >> 6), d = dloc & 63;
            const uint4 v4 = *(const uint4*)&S[dloc * 136 + seg * 8];
            *(uint4*)&vhT[((size_t)((b * 8 + h) * 64 + d)) * 1024 + sbase + seg * 8] = v4;
        }
    } else {
        ushort* out = z ? kh : qh;
#pragma unroll
        for (int it = 0; it < 8; ++it) {
            const int c = it * 256 + tid;
            const int row = c >> 4, seg = c & 15;       // s-local, col-chunk
            const int h = (bn >> 6) + (seg >> 3), d8 = (seg & 7) * 8;
            const uint4 v4 = *(const uint4*)&S[row * 136 + seg * 8];
            *(uint4*)&out[(((size_t)(b * 8 + h)) * 1024 + sbase + row) * 64 + d8] = v4;
        }
    }
}

// ---------------------------------------------------------------------------
// QK^T per (b,h): raw bf16 logits (x0.125) into the first 2KB of each score
// row's 4KB slot, via LDS C-bounce -> coalesced 16B stores. Upper-triangular
// 128-blocks write f32 zeros. Flat grid, bh fastest-varying (XCD L2 share).
// ---------------------------------------------------------------------------
__global__ __launch_bounds__(256)
void qk_mfma(const ushort* __restrict__ qh, const ushort* __restrict__ kh,
             float* __restrict__ scores)
{
    const int d0 = blockIdx.x;           // 0..4095
    const int bh = d0 & 63;
    const int pair = d0 >> 6;            // 0..63
    const int kb = pair & 7, qb = pair >> 3;
    const int tid = threadIdx.x;
    if (kb > qb) {
        // masked region: write final zeros
        float* S = scores + ((size_t)bh << 20);
        const f32x4 z = {};
#pragma unroll
        for (int it = 0; it < 16; ++it) {
            const int f = it * 256 + tid;           // 4096 float4 total
            const int row = f >> 5, c4 = f & 31;
            __builtin_nontemporal_store(z,
                (f32x4*)&S[(size_t)(qb * 128 + row) * 1024 + kb * 128 + c4 * 4]);
        }
        return;
    }
    __shared__ __align__(16) ushort S[128 * 136];   // 34.8 KB
    ushort* As = S;
    ushort* Bs = S + 8192;
    const int lane = tid & 63, wave = tid >> 6;
    const int wr = wave >> 1, wc = wave & 1;
    const ushort* Ab = qh + ((size_t)bh * PS + qb * 128) * 64;
    const ushort* Bb = kh + ((size_t)bh * PS + kb * 128) * 64;

#pragma unroll
    for (int i = 0; i < 4; ++i) {
        const int c = wave * 4 + i;
        gload16(Ab + c * 512 + lane * 8, &As[c * 512]);
        gload16(Bb + c * 512 + lane * 8, &Bs[c * 512]);
    }
    __syncthreads();

    f32x4 acc[4][4] = {};
    short8 af[2][4], bf[2][4];
#pragma unroll
    for (int kk = 0; kk < 2; ++kk) {
#pragma unroll
        for (int m = 0; m < 4; ++m)
            af[kk][m] = *(const short8*)&As[(wr * 64 + m * 16 + (lane & 15)) * 64 + kk * 32 + (lane >> 4) * 8];
#pragma unroll
        for (int n = 0; n < 4; ++n)
            bf[kk][n] = *(const short8*)&Bs[(wc * 64 + n * 16 + (lane & 15)) * 64 + kk * 32 + (lane >> 4) * 8];
    }
#pragma unroll
    for (int kk = 0; kk < 2; ++kk)
#pragma unroll
        for (int m = 0; m < 4; ++m)
#pragma unroll
            for (int n = 0; n < 4; ++n)
                acc[m][n] = __builtin_amdgcn_mfma_f32_16x16x32_bf16(af[kk][m], bf[kk][n], acc[m][n], 0, 0, 0);

    __syncthreads();   // all fragment reads done before C overwrites S

    // ---- stage C bf16 (x0.125) into LDS, stride 136 ----
#pragma unroll
    for (int m = 0; m < 4; ++m)
#pragma unroll
        for (int n = 0; n < 4; ++n) {
            const int r0 = wr * 64 + m * 16 + (lane >> 4) * 4;
            const int cl = wc * 64 + n * 16 + (lane & 15);
#pragma unroll
            for (int r = 0; r < 4; ++r)
                S[(r0 + r) * 136 + cl] = f2bf(acc[m][n][r] * 0.125f);
        }
    __syncthreads();

    // ---- coalesced 16B stores of the raw tile ----
    ushort* Sr = (ushort*)(scores + ((size_t)bh << 20));
#pragma unroll
    for (int it = 0; it < 8; ++it) {
        const int c = it * 256 + tid;
        const int row = c >> 4, seg = c & 15;
        const uint4 v4 = *(const uint4*)&S[row * 136 + seg * 8];
        *(uint4*)&Sr[(size_t)(qb * 128 + row) * 2048 + kb * 128 + seg * 8] = v4;
    }
}

// ---------------------------------------------------------------------------
// Fused row softmax + PV, v3: 512 threads = 8 waves = 8 rows per block.
// Final score stores are REGULAR (cached) stores: L2 merges the 16B chunks
// into full lines (round-12 NT stores showed 2.6x write amplification).
// ---------------------------------------------------------------------------
__global__ __launch_bounds__(512, 8)
void rowpv3(float* __restrict__ scores, const ushort* __restrict__ vhT,
            const float* __restrict__ gammas, ushort* __restrict__ attn)
{
    const int d0 = blockIdx.x;           // 0..8191
    const int bh = d0 & 63, h = bh & 7;
    const int b = bh >> 3;
    const int rb = d0 >> 6;              // 8-row block 0..127
    const int w = threadIdx.x >> 6;      // wave = row within block, 0..7
    const int lane = threadIdx.x & 63;
    const int i = rb * 8 + w;
    const int nt = (rb >> 3) + 1;        // 64-col k-tiles for this block
    const int G = (nt + 3) >> 2;         // 1..4 col-groups of 4 per lane
    const int base = lane * 4 * G;       // covers [0, 256G) >= nt*64
    const int lim = ((i >> 7) + 1) * 128;

    __shared__ __align__(16) ushort P[8 * 1024];    // 16 KB, swizzled
    __shared__ float RED[2][8][68];                 // 4.3 KB padded

    float* srow = scores + ((size_t)bh << 20) + ((size_t)i << 10);
    const ushort* rraw = (const ushort*)srow;

    union U4 { uint2 v; ushort u[4]; };
    float l[16];
#pragma unroll
    for (int g = 0; g < 4; ++g) {
        if (g < G) {
            U4 a; a.v = *(const uint2*)(rraw + base + g * 4);
#pragma unroll
            for (int j = 0; j < 4; ++j)
                l[g * 4 + j] = (base + g * 4 + j <= i) ? bf2f(a.u[j]) : -3.0e38f;
        }
    }

    // softmax-1 max
    float m1 = -3.0e38f;
#pragma unroll
    for (int g = 0; g < 4; ++g) if (g < G)
#pragma unroll
        for (int j = 0; j < 4; ++j) m1 = fmaxf(m1, l[g * 4 + j]);
#pragma unroll
    for (int off = 32; off; off >>= 1) m1 = fmaxf(m1, __shfl_xor(m1, off));

    // lane sum of exp (masked cols underflow to 0)
    float lsum = 0.f;
#pragma unroll
    for (int g = 0; g < 4; ++g) if (g < G)
#pragma unroll
        for (int j = 0; j < 4; ++j) lsum += __expf(l[g * 4 + j] - m1);
    // single 64-lane scan of lane totals
    float incl = lsum;
#pragma unroll
    for (int off = 1; off < 64; off <<= 1) {
        const float y = __shfl_up(incl, off);
        if (lane >= off) incl += y;
    }
    const float excl = incl - lsum;
    const float es = __shfl(incl, 63);
    const float inv_es = __builtin_amdgcn_rcpf(es);
    const float gamma = -fabsf(gammas[h]);
    const float M2 = fmaxf(m1, 0.f);     // shift for softmax-2 (exact)

    // decay + softmax-2 numerator (running cumsum recompute)
    float racc = excl;
    float s2 = 0.f;
#pragma unroll
    for (int g = 0; g < 4; ++g) if (g < G)
#pragma unroll
        for (int j = 0; j < 4; ++j) {
            const int c = g * 4 + j;
            if (base + c <= i) {
                racc += __expf(l[c] - m1);
                const float sfxn = fmaxf((es - racc) * inv_es, 0.f);
                const float pe = (float)(i - (base + c));
                const float dist = __builtin_amdgcn_sqrtf(sfxn * pe);
                const float eff = fmaxf(__expf(gamma * dist), 1e-5f);
                const float p = __expf(l[c] * eff - M2);
                l[c] = p; s2 += p;
            } else {
                l[c] = 0.f;
            }
        }
#pragma unroll
    for (int off = 32; off; off >>= 1) s2 += __shfl_xor(s2, off);
    const float inv2 = __builtin_amdgcn_rcpf(s2);
#pragma unroll
    for (int g = 0; g < 4; ++g) if (g < G)
#pragma unroll
        for (int j = 0; j < 4; ++j) l[g * 4 + j] *= inv2;

    // ---- P -> LDS bf16; logical 16B chunk lc -> physical (lc&~7)|((lc^w)&7)
#pragma unroll
    for (int g = 0; g < 4; ++g) {
        if (g < G) {
            U4 p;
#pragma unroll
            for (int j = 0; j < 4; ++j) p.u[j] = f2bf(l[g * 4 + j]);
            const int col = base + g * 4;
            const int lc = col >> 3;
            const int sp = (lc & ~7) | ((lc ^ w) & 7);
            *(uint2*)&P[w * 1024 + sp * 8 + (col & 7)] = p.v;
        }
    }
    __syncthreads();

    // ---- final f32 score stores: REGULAR stores (L2 write-combining)
#pragma unroll
    for (int g = 0; g < 4; ++g) {
        if (g < G && base + g * 4 < lim) {
            f32x4 v;
            v[0] = l[g * 4 + 0]; v[1] = l[g * 4 + 1];
            v[2] = l[g * 4 + 2]; v[3] = l[g * 4 + 3];
            *(f32x4*)&srow[base + g * 4] = v;
        }
    }

    // ---- PV MFMA: waves (kq in 0..1, nn in 0..3); A rows 8-15 duplicated,
    // their C rows discarded. V^T direct from global (L2).
    const int kq = w >> 2, nn = w & 3;
    const int row16 = lane & 15, kg = lane >> 4;
    const int arow = lane & 7;           // P row supplied to the A-fragment
    const ushort* vb = vhT + ((size_t)bh << 16) + (size_t)(nn * 16 + row16) * 1024;
    f32x4 acc = {};
    for (int t = kq; t < nt; t += 2) {
#pragma unroll
        for (int kk = 0; kk < 2; ++kk) {
            const int chunk = t * 8 + ((kk * 4 + kg) ^ arow);
            const short8 af = *(const short8*)&P[arow * 1024 + chunk * 8];
            const short8 bf = *(const short8*)&vb[t * 64 + kk * 32 + kg * 8];
            acc = __builtin_amdgcn_mfma_f32_16x16x32_bf16(af, bf, acc, 0, 0, 0);
        }
    }

    // ---- reduce 2 kq partials (C rows 0..7 only), write attn
    if (kg < 2) {
#pragma unroll
        for (int r = 0; r < 4; ++r)
            RED[kq][kg * 4 + r][nn * 16 + row16] = acc[r];
    }
    __syncthreads();
    const float o = RED[0][w][lane] + RED[1][w][lane];
    attn[((size_t)(b * 1024 + i)) * 512 + h * 64 + lane] = f2bf(o);
}

// ---------------------------------------------------------------------------
// Output GEMM: f32 out = attn(bf16) @ Wo^T + bo
// ---------------------------------------------------------------------------
__global__ __launch_bounds__(256)
void gemm_out(const ushort* __restrict__ A, const ushort* __restrict__ B,
              const float* __restrict__ bias, float* __restrict__ out)
{
    __shared__ __align__(16) ushort As[128 * 64];
    __shared__ __align__(16) ushort Bs[128 * 64];
    const int tid = threadIdx.x;
    const int lane = tid & 63;
    const int wave = tid >> 6;
    const int wr = wave >> 1, wc = wave & 1;
    const int bm = blockIdx.x * 128, bn = blockIdx.y * 128;
    const int lrow = lane >> 3;
    const int lcol = (lane & 7) * 8;

    f32x4 acc[4][4] = {};

    for (int k0 = 0; k0 < 512; k0 += 64) {
#pragma unroll
        for (int i = 0; i < 4; ++i) {
            const int c = wave * 4 + i;
            gload16(A + (size_t)(bm + c * 8 + lrow) * 512 + k0 + lcol, &As[c * 512]);
            gload16(B + (size_t)(bn + c * 8 + lrow) * 512 + k0 + lcol, &Bs[c * 512]);
        }
        __syncthreads();
        short8 af[2][4], bf[2][4];
#pragma unroll
        for (int kk = 0; kk < 2; ++kk) {
#pragma unroll
            for (int m = 0; m < 4; ++m)
                af[kk][m] = *(const short8*)&As[(wr * 64 + m * 16 + (lane & 15)) * 64 + kk * 32 + (lane >> 4) * 8];
#pragma unroll
            for (int n = 0; n < 4; ++n)
                bf[kk][n] = *(const short8*)&Bs[(wc * 64 + n * 16 + (lane & 15)) * 64 + kk * 32 + (lane >> 4) * 8];
        }
#pragma unroll
        for (int kk = 0; kk < 2; ++kk)
#pragma unroll
            for (int m = 0; m < 4; ++m)
#pragma unroll
                for (int n = 0; n < 4; ++n)
                    acc[m][n] = __builtin_amdgcn_mfma_f32_16x16x32_bf16(af[kk][m], bf[kk][n], acc[m][n], 0, 0, 0);
        __syncthreads();
    }

#pragma unroll
    for (int m = 0; m < 4; ++m)
#pragma unroll
        for (int n = 0; n < 4; ++n)
#pragma unroll
            for (int r = 0; r < 4; ++r) {
                const int row = bm + wr * 64 + m * 16 + (lane >> 4) * 4 + r;
                const int col = bn + wc * 64 + n * 16 + (lane & 15);
                out[(size_t)row * 512 + col] = acc[m][n][r] + bias[col];
            }
}

// ---------------------------------------------------------------------------
extern "C" void kernel_launch(void* const* d_in, const int* in_sizes, int n_in,
                              void* d_out, int out_size, void* d_ws, size_t ws_size,
                              hipStream_t stream)
{
    const float* q      = (const float*)d_in[0];
    const float* k      = (const float*)d_in[1];
    const float* v      = (const float*)d_in[2];
    const float* Wq     = (const float*)d_in[4];
    const float* bq     = (const float*)d_in[5];
    const float* Wv     = (const float*)d_in[6];
    const float* bv     = (const float*)d_in[7];
    const float* Wo     = (const float*)d_in[8];
    const float* bo     = (const float*)d_in[9];
    const float* gammas = (const float*)d_in[10];

    float* out    = (float*)d_out;                       // [8,1024,512] f32
    float* scores = out + (size_t)PB * PS * PD;          // [64,1024,1024] f32

    char* w = (char*)d_ws;
    ushort* q_bf  = (ushort*)(w);                        // 8 MB
    ushort* k_bf  = (ushort*)(w + (8u  << 20));          // 8 MB
    ushort* v_bf  = (ushort*)(w + (16u << 20));          // 8 MB
    ushort* Wq_bf = (ushort*)(w + (24u << 20));          // 0.5 MB
    ushort* Wv_bf = (ushort*)(w + (24u << 20) + (1u << 19));
    ushort* Wo_bf = (ushort*)(w + (25u << 20));
    ushort* qh    = (ushort*)(w + (26u << 20));          // 8 MB
    ushort* kh    = (ushort*)(w + (34u << 20));          // 8 MB
    ushort* vhT   = (ushort*)(w + (42u << 20));          // 8 MB (plain transpose)
    ushort* attn  = (ushort*)(w + (50u << 20));          // 8 MB

    cast_all<<<13056, 256, 0, stream>>>(q, k, v, Wq, Wv, Wo,
                                        q_bf, k_bf, v_bf, Wq_bf, Wv_bf, Wo_bf);

    proj3<<<dim3(64, 4, 3), 256, 0, stream>>>(q_bf, k_bf, v_bf, Wq_bf, Wv_bf,
                                              bq, bv, qh, kh, vhT);

    qk_mfma<<<4096, 256, 0, stream>>>(qh, kh, scores);
    rowpv3<<<8192, 512, 0, stream>>>(scores, vhT, gammas, attn);

    gemm_out<<<dim3(64, 4), 256, 0, stream>>>(attn, Wo_bf, bo, out);
}